// Round 2
// baseline (19473.857 us; speedup 1.0000x reference)
//
#include <hip/hip_runtime.h>
#include <cstdint>
#include <cstddef>

// Problem dims
#define NT   256     // T
#define NB   64      // B
#define XD   128
#define HD   1024
#define ZD   128
#define H3   3072
#define TBM  16384   // T*B

typedef __attribute__((ext_vector_type(8))) short bf16x8;
typedef __attribute__((ext_vector_type(4))) float f32x4;

__device__ __forceinline__ unsigned short f2bf(float f){
  unsigned int u = __float_as_uint(f);
  u += 0x7fffu + ((u >> 16) & 1u);
  return (unsigned short)(u >> 16);
}
__device__ __forceinline__ float bf2f(unsigned short h){
  return __uint_as_float(((unsigned int)h) << 16);
}

// ---------------- convert f32 -> bf16 ----------------
__global__ void cvt_bf16(const float* __restrict__ src, unsigned short* __restrict__ dst, int n){
  for (int i = blockIdx.x*blockDim.x + threadIdx.x; i < n; i += gridDim.x*blockDim.x)
    dst[i] = f2bf(src[i]);
}

// ---------------- generic bf16 MFMA GEMM ----------------
// C[m_local, n] = act( sum_k A(m0+m_local, k) * W[n,k] + bias[n] )
// A(m,k): k <  K1 -> A1[rmap(m,rev1)*K1 + k]
//         k >= K1 -> A2[rmap(m,rev2)*(K-K1) + (k-K1)]
// rmap(m,1) = (255 - t)*64 + b  (time reversal), m = t*64+b (global row)
// ACT: 0 none, 1 relu, 2 sigmoid, 3 softplus.  OUT_BF: write bf16 else f32.
template<int ACT, int OUT_BF, int BIAS>
__launch_bounds__(256)
__global__ void gemm_bf16(const unsigned short* __restrict__ A1, int rev1, int K1,
                          const unsigned short* __restrict__ A2, int rev2, int K,
                          const unsigned short* __restrict__ W,
                          const float* __restrict__ bias,
                          void* __restrict__ Cv, int N, int m0)
{
  __shared__ __align__(16) unsigned short As[128][40];
  __shared__ __align__(16) unsigned short Ws[128][40];
  const int tid   = threadIdx.x;
  const int mbase = blockIdx.y * 128;     // local row base (C index)
  const int nbase = blockIdx.x * 128;
  const int wid = tid >> 6, lane = tid & 63;
  const int wr = wid >> 1, wc = wid & 1;
  const int fr = lane & 15;
  const int kc = (lane >> 4) * 8;
  const int K2 = K - K1;
  const int nk = K >> 5;

  f32x4 acc[4][4];
  #pragma unroll
  for (int i = 0; i < 4; ++i)
    #pragma unroll
    for (int j = 0; j < 4; ++j)
      acc[i][j] = (f32x4){0.f, 0.f, 0.f, 0.f};

  for (int ks = 0; ks < nk; ++ks){
    const int k0 = ks << 5;
    __syncthreads();
    // stage A tile 128x32
    for (int l = tid; l < 512; l += 256){
      int row = l >> 2, c = l & 3;
      int kk = k0 + c*8;
      int m = m0 + mbase + row;           // global row for A mapping
      uint4 v;
      if (kk < K1){
        int mm = rev1 ? (((255 - (m >> 6)) << 6) | (m & 63)) : m;
        v = *(const uint4*)(A1 + (size_t)mm * K1 + kk);
      } else {
        int mm = rev2 ? (((255 - (m >> 6)) << 6) | (m & 63)) : m;
        v = *(const uint4*)(A2 + (size_t)mm * K2 + (kk - K1));
      }
      *(uint4*)&As[row][c*8] = v;
    }
    // stage W tile 128x32
    for (int l = tid; l < 512; l += 256){
      int row = l >> 2, c = l & 3;
      uint4 v = *(const uint4*)(W + (size_t)(nbase + row) * K + k0 + c*8);
      *(uint4*)&Ws[row][c*8] = v;
    }
    __syncthreads();
    bf16x8 af[4], bfm[4];
    #pragma unroll
    for (int f = 0; f < 4; ++f) af[f]  = *(const bf16x8*)&As[wr*64 + f*16 + fr][kc];
    #pragma unroll
    for (int f = 0; f < 4; ++f) bfm[f] = *(const bf16x8*)&Ws[wc*64 + f*16 + fr][kc];
    #pragma unroll
    for (int i = 0; i < 4; ++i)
      #pragma unroll
      for (int j = 0; j < 4; ++j)
        acc[i][j] = __builtin_amdgcn_mfma_f32_16x16x32_bf16(af[i], bfm[j], acc[i][j], 0, 0, 0);
  }

  // epilogue: C/D layout col = lane&15, row = (lane>>4)*4 + r
  #pragma unroll
  for (int i = 0; i < 4; ++i){
    #pragma unroll
    for (int j = 0; j < 4; ++j){
      #pragma unroll
      for (int r = 0; r < 4; ++r){
        int row = mbase + wr*64 + i*16 + (lane >> 4)*4 + r;
        int col = nbase + wc*64 + j*16 + fr;
        float v = acc[i][j][r];
        if (BIAS) v += bias[col];
        if (ACT == 1) v = fmaxf(v, 0.f);
        else if (ACT == 2) v = 1.f / (1.f + expf(-v));
        else if (ACT == 3) v = (v > 20.f) ? v : log1pf(expf(v));
        if (OUT_BF) ((unsigned short*)Cv)[(size_t)row * N + col] = f2bf(v);
        else        ((float*)Cv)[(size_t)row * N + col] = v;
      }
    }
  }
}

// ---------------- fused GRU step ----------------
__launch_bounds__(192)
__global__ void gru_step(const unsigned short* __restrict__ W3,
                         const unsigned short* __restrict__ gi,     // [64,3072] bf16 (this t)
                         const unsigned short* __restrict__ hin_bf, // [64,1024]
                         const float*          __restrict__ hin,    // [64,1024] f32
                         float*                __restrict__ hout,   // [64,1024] f32
                         unsigned short*       __restrict__ hout_bf)// [64,1024] bf16
{
  __shared__ __align__(16) unsigned short Hs[64][40];
  __shared__ __align__(16) unsigned short Wsh[3][32][40];
  __shared__ float ghs[3][64][33];
  const int tid = threadIdx.x;
  const int j0 = blockIdx.x * 32;
  const int wid = tid >> 6, lane = tid & 63;
  const int fr = lane & 15;
  const int kc = (lane >> 4) * 8;

  f32x4 acc[4][2];
  #pragma unroll
  for (int i = 0; i < 4; ++i){ acc[i][0] = (f32x4){0.f,0.f,0.f,0.f}; acc[i][1] = (f32x4){0.f,0.f,0.f,0.f}; }

  for (int ks = 0; ks < 32; ++ks){
    const int k0 = ks << 5;
    __syncthreads();
    for (int l = tid; l < 256; l += 192){           // stage h tile 64x32
      int row = l >> 2, c = l & 3;
      *(uint4*)&Hs[row][c*8] = *(const uint4*)(hin_bf + (size_t)row*HD + k0 + c*8);
    }
    for (int l = tid; l < 384; l += 192){           // stage 3 gate W tiles 32x32
      int g = l >> 7, r = (l >> 2) & 31, c = l & 3;
      *(uint4*)&Wsh[g][r][c*8] = *(const uint4*)(W3 + (size_t)(g*HD + j0 + r)*HD + k0 + c*8);
    }
    __syncthreads();
    bf16x8 b0 = *(const bf16x8*)&Wsh[wid][fr][kc];
    bf16x8 b1 = *(const bf16x8*)&Wsh[wid][16 + fr][kc];
    #pragma unroll
    for (int fm = 0; fm < 4; ++fm){
      bf16x8 a = *(const bf16x8*)&Hs[fm*16 + fr][kc];
      acc[fm][0] = __builtin_amdgcn_mfma_f32_16x16x32_bf16(a, b0, acc[fm][0], 0, 0, 0);
      acc[fm][1] = __builtin_amdgcn_mfma_f32_16x16x32_bf16(a, b1, acc[fm][1], 0, 0, 0);
    }
  }
  __syncthreads();
  #pragma unroll
  for (int fm = 0; fm < 4; ++fm)
    #pragma unroll
    for (int fn = 0; fn < 2; ++fn)
      #pragma unroll
      for (int r = 0; r < 4; ++r)
        ghs[wid][fm*16 + (lane >> 4)*4 + r][fn*16 + fr] = acc[fm][fn][r];
  __syncthreads();

  for (int idx = tid; idx < 2048; idx += 192){
    int b = idx >> 5, j = idx & 31;
    int col = j0 + j;
    float gr = ghs[0][b][j], gz = ghs[1][b][j], gn = ghs[2][b][j];
    float ir  = bf2f(gi[b*H3 + col]);
    float iz  = bf2f(gi[b*H3 + HD + col]);
    float inn = bf2f(gi[b*H3 + 2*HD + col]);
    float r = 1.f / (1.f + expf(-(ir + gr)));
    float z = 1.f / (1.f + expf(-(iz + gz)));
    float n = tanhf(inn + r * gn);
    float hp = hin[b*HD + col];
    float h = (1.f - z) * n + z * hp;
    hout[b*HD + col] = h;
    hout_bf[b*HD + col] = f2bf(h);
  }
}

// ---------------- z = eps*enc_std + enc_mean (bf16 out) ----------------
__global__ void z_make(const float* __restrict__ eps, const float* __restrict__ em,
                       const float* __restrict__ es, unsigned short* __restrict__ zb, int n){
  for (int i = blockIdx.x*blockDim.x + threadIdx.x; i < n; i += gridDim.x*blockDim.x)
    zb[i] = f2bf(eps[i] * es[i] + em[i]);
}

// ---------------- reductions ----------------
__global__ void kld_partial(const float* __restrict__ em, const float* __restrict__ es,
                            const float* __restrict__ pm, const float* __restrict__ ps,
                            float* __restrict__ part, int n){
  float s = 0.f;
  for (int i = blockIdx.x*blockDim.x + threadIdx.x; i < n; i += gridDim.x*blockDim.x){
    float e = es[i], p = ps[i], d = em[i] - pm[i];
    s += 2.f*(logf(p) - logf(e)) + (e*e + d*d)/(p*p) - 1.f;
  }
  __shared__ float red[256];
  red[threadIdx.x] = s; __syncthreads();
  for (int off = 128; off; off >>= 1){
    if (threadIdx.x < off) red[threadIdx.x] += red[threadIdx.x + off];
    __syncthreads();
  }
  if (threadIdx.x == 0) part[blockIdx.x] = red[0];
}

__global__ void nll_partial(const float* __restrict__ y, const float* __restrict__ dm,
                            float* __restrict__ part, int n){
  float s = 0.f;
  for (int i = blockIdx.x*blockDim.x + threadIdx.x; i < n; i += gridDim.x*blockDim.x){
    float yy = y[i], d = dm[i];
    s += yy * logf(d) + (1.f - yy) * logf(1.f - d);
  }
  __shared__ float red[256];
  red[threadIdx.x] = s; __syncthreads();
  for (int off = 128; off; off >>= 1){
    if (threadIdx.x < off) red[threadIdx.x] += red[threadIdx.x + off];
    __syncthreads();
  }
  if (threadIdx.x == 0) part[blockIdx.x] = red[0];
}

__global__ void final_sum(const float* __restrict__ part, int n, float scale, float* __restrict__ out){
  float s = 0.f;
  for (int i = threadIdx.x; i < n; i += 256) s += part[i];
  __shared__ float red[256];
  red[threadIdx.x] = s; __syncthreads();
  for (int off = 128; off; off >>= 1){
    if (threadIdx.x < off) red[threadIdx.x] += red[threadIdx.x + off];
    __syncthreads();
  }
  if (threadIdx.x == 0) out[0] = scale * red[0];
}

// ---------------- host ----------------
extern "C" void kernel_launch(void* const* d_in, const int* in_sizes, int n_in,
                              void* d_out, int out_size, void* d_ws, size_t ws_size,
                              hipStream_t stream)
{
  const float* x   = (const float*)d_in[0];
  const float* y   = (const float*)d_in[1];
  const float* eps = (const float*)d_in[2];
  const float* enc_b1 = (const float*)d_in[8];
  const float* enc_b2 = (const float*)d_in[10];
  const float* encm_b = (const float*)d_in[12];
  const float* encs_b = (const float*)d_in[14];
  const float* pr_b   = (const float*)d_in[16];
  const float* prm_b  = (const float*)d_in[18];
  const float* prs_b  = (const float*)d_in[20];
  const float* dec_b1 = (const float*)d_in[22];
  const float* dec_b2 = (const float*)d_in[24];
  const float* decm_b = (const float*)d_in[26];
  const float* decs_b = (const float*)d_in[28];

  // ---- workspace layout (total ~164 MiB) ----
  char* ws = (char*)d_ws;
  size_t off = 0;
  auto alloc = [&](size_t bytes){ size_t o = off; off += (bytes + 255) & ~(size_t)255; return o; };
  const size_t o_big   = alloc((size_t)71303168);       // 68 MiB phase-union region
  const size_t o_hseq  = alloc((size_t)TBM * HD * 2);   // h_seq bf16 (32 MiB)
  const size_t o_aseq  = alloc((size_t)TBM * HD * 2);   // a_fwd bf16 (32 MiB)
  const size_t o_wbf   = alloc((size_t)16384000 * 2);   // all weights bf16 (~31.3 MiB)
  const size_t o_ping  = alloc((size_t)2 * NB * HD * 4);
  const size_t o_zbf0  = alloc((size_t)NB * HD * 2);    // zero bf16 h
  const size_t o_pkld  = alloc((size_t)1024 * 4);
  const size_t o_pnll  = alloc((size_t)1024 * 4);
  (void)off; (void)ws_size;

  char* big = ws + o_big;
  // phase A (GRUs): gi half-chunk [8192,3072] bf16 (48 MiB) + xbf + ybf
  unsigned short* gih = (unsigned short*)(big);
  unsigned short* xbf = (unsigned short*)(big + 50331648);
  unsigned short* ybf = (unsigned short*)(big + 54525952);
  // phase B (MLPs): tA (32 MiB) + tB (32 MiB) + zbf (4 MiB)
  unsigned short* tA  = (unsigned short*)(big);
  unsigned short* tB  = (unsigned short*)(big + 33554432);
  unsigned short* zbf = (unsigned short*)(big + 67108864);

  unsigned short* hseq = (unsigned short*)(ws + o_hseq);
  unsigned short* aseq = (unsigned short*)(ws + o_aseq);
  unsigned short* wbf  = (unsigned short*)(ws + o_wbf);
  float* ping = (float*)(ws + o_ping);
  unsigned short* zbf0 = (unsigned short*)(ws + o_zbf0);
  float* pkld = (float*)(ws + o_pkld);
  float* pnll = (float*)(ws + o_pnll);

  // weight bf16 sub-offsets (elements)
  const int   widx[15] = {3,4,5,6,7,9,11,13,15,17,19,21,23,25,27};
  const size_t wsz[15] = {393216,3145728,3538944,3145728,1048576,1048576,131072,131072,
                          1048576,131072,131072,1179648,1048576,131072,131072};
  size_t woff[15]; { size_t a = 0; for (int i = 0; i < 15; ++i){ woff[i] = a; a += wsz[i]; } }
  unsigned short* w_hWih = wbf + woff[0];
  unsigned short* w_hWhh = wbf + woff[1];
  unsigned short* w_aWih = wbf + woff[2];
  unsigned short* w_aWhh = wbf + woff[3];
  unsigned short* w_enc1 = wbf + woff[4];
  unsigned short* w_enc2 = wbf + woff[5];
  unsigned short* w_encm = wbf + woff[6];
  unsigned short* w_encs = wbf + woff[7];
  unsigned short* w_pr   = wbf + woff[8];
  unsigned short* w_prm  = wbf + woff[9];
  unsigned short* w_prs  = wbf + woff[10];
  unsigned short* w_dec1 = wbf + woff[11];
  unsigned short* w_dec2 = wbf + woff[12];
  unsigned short* w_decm = wbf + woff[13];
  unsigned short* w_decs = wbf + woff[14];

  float* out = (float*)d_out;
  float* em_out = out + 2;
  float* es_out = out + 2 + 2097152;
  float* dm_out = out + 2 + 2*2097152;   // doubles as pm scratch before decoder
  float* ds_out = out + 2 + 3*2097152;   // doubles as ps scratch before decoder
  float* pm = dm_out;
  float* ps = ds_out;

  // --- converts ---
  cvt_bf16<<<256, 256, 0, stream>>>(x, xbf, TBM*XD);
  cvt_bf16<<<256, 256, 0, stream>>>(y, ybf, TBM*XD);
  for (int i = 0; i < 15; ++i)
    cvt_bf16<<<256, 256, 0, stream>>>((const float*)d_in[widx[i]], wbf + woff[i], (int)wsz[i]);
  hipMemsetAsync(zbf0, 0, (size_t)NB*HD*2, stream);

  const dim3 blk(256);
  const dim3 gHalf3072(H3/128, 64);     // 8192 rows
  const dim3 g1024(HD/128, TBM/128);
  const dim3 g128(1, TBM/128);

  // --- GRU 1 (time-chunked gi: 2 x 128 steps) ---
  hipMemsetAsync(ping, 0, (size_t)NB*HD*4, stream);
  for (int c = 0; c < 2; ++c){
    gemm_bf16<0,1,0><<<gHalf3072, blk, 0, stream>>>(xbf, 0, XD, (const unsigned short*)nullptr, 0, XD,
                                                    w_hWih, nullptr, gih, H3, c*8192);
    for (int tt = 0; tt < 128; ++tt){
      int t = c*128 + tt;
      const unsigned short* hbf = (t == 0) ? zbf0 : (hseq + (size_t)(t-1)*NB*HD);
      gru_step<<<32, 192, 0, stream>>>(w_hWhh, gih + (size_t)tt*NB*H3, hbf,
                                       ping + (size_t)(t & 1)*NB*HD,
                                       ping + (size_t)((t+1) & 1)*NB*HD,
                                       hseq + (size_t)t*NB*HD);
    }
  }

  // --- GRU 2 (input [y_rev | h_rev], output stored reversed => a_fwd) ---
  hipMemsetAsync(ping, 0, (size_t)NB*HD*4, stream);
  for (int c = 0; c < 2; ++c){
    gemm_bf16<0,1,0><<<gHalf3072, blk, 0, stream>>>(ybf, 1, XD, hseq, 1, XD + HD,
                                                    w_aWih, nullptr, gih, H3, c*8192);
    for (int tt = 0; tt < 128; ++tt){
      int t = c*128 + tt;   // reversed-time index
      const unsigned short* hbf = (t == 0) ? zbf0 : (aseq + (size_t)(NT - t)*NB*HD);
      gru_step<<<32, 192, 0, stream>>>(w_aWhh, gih + (size_t)tt*NB*H3, hbf,
                                       ping + (size_t)(t & 1)*NB*HD,
                                       ping + (size_t)((t+1) & 1)*NB*HD,
                                       aseq + (size_t)(NT - 1 - t)*NB*HD);
    }
  }

  // --- encoder ---
  gemm_bf16<1,1,1><<<g1024, blk, 0, stream>>>(aseq, 0, HD, (const unsigned short*)nullptr, 0, HD,
                                              w_enc1, enc_b1, tA, HD, 0);
  gemm_bf16<1,1,1><<<g1024, blk, 0, stream>>>(tA, 0, HD, (const unsigned short*)nullptr, 0, HD,
                                              w_enc2, enc_b2, tB, HD, 0);
  gemm_bf16<0,0,1><<<g128, blk, 0, stream>>>(tB, 0, HD, (const unsigned short*)nullptr, 0, HD,
                                             w_encm, encm_b, em_out, ZD, 0);
  gemm_bf16<3,0,1><<<g128, blk, 0, stream>>>(tB, 0, HD, (const unsigned short*)nullptr, 0, HD,
                                             w_encs, encs_b, es_out, ZD, 0);
  z_make<<<2048, 256, 0, stream>>>(eps, em_out, es_out, zbf, TBM*ZD);

  // --- prior (pm/ps into dm/ds regions; kld BEFORE decoder overwrites them) ---
  gemm_bf16<1,1,1><<<g1024, blk, 0, stream>>>(hseq, 1, HD, (const unsigned short*)nullptr, 1, HD,
                                              w_pr, pr_b, tA, HD, 0);
  gemm_bf16<0,0,1><<<g128, blk, 0, stream>>>(tA, 0, HD, (const unsigned short*)nullptr, 0, HD,
                                             w_prm, prm_b, pm, ZD, 0);
  gemm_bf16<3,0,1><<<g128, blk, 0, stream>>>(tA, 0, HD, (const unsigned short*)nullptr, 0, HD,
                                             w_prs, prs_b, ps, ZD, 0);
  kld_partial<<<1024, 256, 0, stream>>>(em_out, es_out, pm, ps, pkld, TBM*ZD);
  final_sum<<<1, 256, 0, stream>>>(pkld, 1024, 0.5f, out + 0);

  // --- decoder ---
  gemm_bf16<1,1,1><<<g1024, blk, 0, stream>>>(zbf, 0, ZD, hseq, 1, ZD + HD,
                                              w_dec1, dec_b1, tA, HD, 0);
  gemm_bf16<1,1,1><<<g1024, blk, 0, stream>>>(tA, 0, HD, (const unsigned short*)nullptr, 0, HD,
                                              w_dec2, dec_b2, tB, HD, 0);
  gemm_bf16<2,0,1><<<g128, blk, 0, stream>>>(tB, 0, HD, (const unsigned short*)nullptr, 0, HD,
                                             w_decm, decm_b, dm_out, ZD, 0);
  gemm_bf16<3,0,1><<<g128, blk, 0, stream>>>(tB, 0, HD, (const unsigned short*)nullptr, 0, HD,
                                             w_decs, decs_b, ds_out, ZD, 0);

  // --- nll ---
  nll_partial<<<1024, 256, 0, stream>>>(y, dm_out, pnll, TBM*XD);
  final_sum<<<1, 256, 0, stream>>>(pnll, 1024, -1.0f, out + 1);
}

// Round 3
// 10156.650 us; speedup vs baseline: 1.9174x; 1.9174x over previous
//
#include <hip/hip_runtime.h>
#include <cstdint>
#include <cstddef>

// Problem dims
#define NT   256     // T
#define NB   64      // B
#define XD   128
#define HD   1024
#define ZD   128
#define H3   3072
#define TBM  16384   // T*B

typedef __attribute__((ext_vector_type(8))) short bf16x8;
typedef __attribute__((ext_vector_type(4))) float f32x4;

__device__ __forceinline__ unsigned short f2bf(float f){
  unsigned int u = __float_as_uint(f);
  u += 0x7fffu + ((u >> 16) & 1u);
  return (unsigned short)(u >> 16);
}
__device__ __forceinline__ float bf2f(unsigned short h){
  return __uint_as_float(((unsigned int)h) << 16);
}

// ---------------- convert f32 -> bf16 ----------------
__global__ void cvt_bf16(const float* __restrict__ src, unsigned short* __restrict__ dst, int n){
  for (int i = blockIdx.x*blockDim.x + threadIdx.x; i < n; i += gridDim.x*blockDim.x)
    dst[i] = f2bf(src[i]);
}

// ---------------- generic bf16 MFMA GEMM (unchanged from round 2) ----------------
template<int ACT, int OUT_BF, int BIAS>
__launch_bounds__(256)
__global__ void gemm_bf16(const unsigned short* __restrict__ A1, int rev1, int K1,
                          const unsigned short* __restrict__ A2, int rev2, int K,
                          const unsigned short* __restrict__ W,
                          const float* __restrict__ bias,
                          void* __restrict__ Cv, int N, int m0)
{
  __shared__ __align__(16) unsigned short As[128][40];
  __shared__ __align__(16) unsigned short Ws[128][40];
  const int tid   = threadIdx.x;
  const int mbase = blockIdx.y * 128;
  const int nbase = blockIdx.x * 128;
  const int wid = tid >> 6, lane = tid & 63;
  const int wr = wid >> 1, wc = wid & 1;
  const int fr = lane & 15;
  const int kc = (lane >> 4) * 8;
  const int K2 = K - K1;
  const int nk = K >> 5;

  f32x4 acc[4][4];
  #pragma unroll
  for (int i = 0; i < 4; ++i)
    #pragma unroll
    for (int j = 0; j < 4; ++j)
      acc[i][j] = (f32x4){0.f, 0.f, 0.f, 0.f};

  for (int ks = 0; ks < nk; ++ks){
    const int k0 = ks << 5;
    __syncthreads();
    for (int l = tid; l < 512; l += 256){
      int row = l >> 2, c = l & 3;
      int kk = k0 + c*8;
      int m = m0 + mbase + row;
      uint4 v;
      if (kk < K1){
        int mm = rev1 ? (((255 - (m >> 6)) << 6) | (m & 63)) : m;
        v = *(const uint4*)(A1 + (size_t)mm * K1 + kk);
      } else {
        int mm = rev2 ? (((255 - (m >> 6)) << 6) | (m & 63)) : m;
        v = *(const uint4*)(A2 + (size_t)mm * K2 + (kk - K1));
      }
      *(uint4*)&As[row][c*8] = v;
    }
    for (int l = tid; l < 512; l += 256){
      int row = l >> 2, c = l & 3;
      uint4 v = *(const uint4*)(W + (size_t)(nbase + row) * K + k0 + c*8);
      *(uint4*)&Ws[row][c*8] = v;
    }
    __syncthreads();
    bf16x8 af[4], bfm[4];
    #pragma unroll
    for (int f = 0; f < 4; ++f) af[f]  = *(const bf16x8*)&As[wr*64 + f*16 + fr][kc];
    #pragma unroll
    for (int f = 0; f < 4; ++f) bfm[f] = *(const bf16x8*)&Ws[wc*64 + f*16 + fr][kc];
    #pragma unroll
    for (int i = 0; i < 4; ++i)
      #pragma unroll
      for (int j = 0; j < 4; ++j)
        acc[i][j] = __builtin_amdgcn_mfma_f32_16x16x32_bf16(af[i], bfm[j], acc[i][j], 0, 0, 0);
  }

  #pragma unroll
  for (int i = 0; i < 4; ++i){
    #pragma unroll
    for (int j = 0; j < 4; ++j){
      #pragma unroll
      for (int r = 0; r < 4; ++r){
        int row = mbase + wr*64 + i*16 + (lane >> 4)*4 + r;
        int col = nbase + wc*64 + j*16 + fr;
        float v = acc[i][j][r];
        if (BIAS) v += bias[col];
        if (ACT == 1) v = fmaxf(v, 0.f);
        else if (ACT == 2) v = 1.f / (1.f + expf(-v));
        else if (ACT == 3) v = (v > 20.f) ? v : log1pf(expf(v));
        if (OUT_BF) ((unsigned short*)Cv)[(size_t)row * N + col] = f2bf(v);
        else        ((float*)Cv)[(size_t)row * N + col] = v;
      }
    }
  }
}

// ---------------- persistent GRU sequence kernel ----------------
// 64 blocks x 256 threads. Block b owns output columns [16b, 16b+16) of all 3 gates.
// W slice (3x16x1024 bf16 = 96KB) lives in LDS in MFMA-fragment order.
// h(t-1) is read from seq[out_off + dir*(t-1)] (bf16), staged in swizzled LDS chunks.
// Cross-block sync: monotone device-scope atomic counter.
__device__ __forceinline__ void gbar(unsigned int* bar, unsigned int target){
  __syncthreads();
  if (threadIdx.x == 0){
    __threadfence();
    __hip_atomic_fetch_add(bar, 1u, __ATOMIC_ACQ_REL, __HIP_MEMORY_SCOPE_AGENT);
    while (__hip_atomic_load(bar, __ATOMIC_ACQUIRE, __HIP_MEMORY_SCOPE_AGENT) < target)
      __builtin_amdgcn_s_sleep(2);
  }
  __syncthreads();
}

__global__ __launch_bounds__(256, 1)
void gru_seq(const unsigned short* __restrict__ W3,   // [3072][1024] bf16
             const unsigned short* __restrict__ gi,   // [nsteps][64][3072] bf16
             unsigned short* __restrict__ seq,        // [256][64][1024] bf16 (h_seq or a_seq)
             float* __restrict__ hstate,              // [64][1024] f32 carry between launches
             unsigned int* __restrict__ bar,
             int t0, int dir, int out_off, int nsteps)
{
  __shared__ __align__(16) uint4 Wf[32][3][64];       // 96KB: [kstep][gate][lane] fragments
  __shared__ __align__(16) char  hb[64*256];          // 16KB swizzled h chunk [64 rows][128 k]
  const int tid  = threadIdx.x;
  const int c0   = blockIdx.x * 16;
  const int wid  = tid >> 6, lane = tid & 63;
  const int fr   = lane & 15, q = lane >> 4;
  const int rowb = wid*16 + q*4;                      // first of this thread's 4 acc rows

  // one-time: W fragments into LDS (wave w loads ksteps w*8..w*8+8)
  for (int ks = wid*8; ks < wid*8 + 8; ++ks)
    #pragma unroll
    for (int g = 0; g < 3; ++g)
      Wf[ks][g][lane] = *(const uint4*)(W3 + (size_t)(g*HD + c0 + fr)*HD + ks*32 + q*8);

  float hc[4];
  if (t0 == 0){
    hc[0] = hc[1] = hc[2] = hc[3] = 0.f;
  } else {
    #pragma unroll
    for (int r = 0; r < 4; ++r)
      hc[r] = hstate[(size_t)(rowb + r)*HD + c0 + fr];
  }
  __syncthreads();

  for (int tt = 0; tt < nsteps; ++tt){
    const int t = t0 + tt;
    // prefetch gi gate inputs (independent of h -> hides under MFMA loop)
    float ir[4], iz[4], inn[4];
    {
      const unsigned short* gb = gi + (size_t)tt*NB*H3;
      #pragma unroll
      for (int r = 0; r < 4; ++r){
        const unsigned short* p = gb + (size_t)(rowb + r)*H3 + c0 + fr;
        ir[r]  = bf2f(p[0]);
        iz[r]  = bf2f(p[HD]);
        inn[r] = bf2f(p[2*HD]);
      }
    }

    f32x4 aR = (f32x4){0.f,0.f,0.f,0.f};
    f32x4 aZ = (f32x4){0.f,0.f,0.f,0.f};
    f32x4 aN = (f32x4){0.f,0.f,0.f,0.f};

    if (t > 0){
      const unsigned short* hp = seq + (size_t)(out_off + dir*(t-1))*NB*HD;
      for (int ch = 0; ch < 8; ++ch){
        __syncthreads();
        #pragma unroll
        for (int i = tid; i < 1024; i += 256){
          int row = i >> 4, c16 = i & 15;
          uint4 v = *(const uint4*)(hp + (size_t)row*HD + ch*128 + c16*8);
          *(uint4*)(hb + row*256 + ((c16*16) ^ ((row & 7) << 4))) = v;
        }
        __syncthreads();
        #pragma unroll
        for (int kss = 0; kss < 4; ++kss){
          const int row = wid*16 + fr;
          bf16x8 a = *(const bf16x8*)(hb + row*256 + ((kss*64 + q*16) ^ ((row & 7) << 4)));
          const int ks = ch*4 + kss;
          aR = __builtin_amdgcn_mfma_f32_16x16x32_bf16(a, *(const bf16x8*)&Wf[ks][0][lane], aR, 0, 0, 0);
          aZ = __builtin_amdgcn_mfma_f32_16x16x32_bf16(a, *(const bf16x8*)&Wf[ks][1][lane], aZ, 0, 0, 0);
          aN = __builtin_amdgcn_mfma_f32_16x16x32_bf16(a, *(const bf16x8*)&Wf[ks][2][lane], aN, 0, 0, 0);
        }
      }
    }

    // gate math, fp32, fully in-register (acc row = q*4+r, col = fr)
    unsigned short hv[4];
    #pragma unroll
    for (int r = 0; r < 4; ++r){
      float rr = 1.f / (1.f + expf(-(ir[r] + aR[r])));
      float zz = 1.f / (1.f + expf(-(iz[r] + aZ[r])));
      float nn = tanhf(inn[r] + rr * aN[r]);
      hc[r] = (1.f - zz) * nn + zz * hc[r];
      hv[r] = f2bf(hc[r]);
    }
    {
      unsigned short* so = seq + (size_t)(out_off + dir*t)*NB*HD + (size_t)rowb*HD + c0 + fr;
      #pragma unroll
      for (int r = 0; r < 4; ++r) so[(size_t)r*HD] = hv[r];
    }

    if (tt < nsteps - 1) gbar(bar, (unsigned int)(tt + 1) * 64u);
  }

  #pragma unroll
  for (int r = 0; r < 4; ++r)
    hstate[(size_t)(rowb + r)*HD + c0 + fr] = hc[r];
}

// ---------------- z = eps*enc_std + enc_mean (bf16 out) ----------------
__global__ void z_make(const float* __restrict__ eps, const float* __restrict__ em,
                       const float* __restrict__ es, unsigned short* __restrict__ zb, int n){
  for (int i = blockIdx.x*blockDim.x + threadIdx.x; i < n; i += gridDim.x*blockDim.x)
    zb[i] = f2bf(eps[i] * es[i] + em[i]);
}

// ---------------- reductions ----------------
__global__ void kld_partial(const float* __restrict__ em, const float* __restrict__ es,
                            const float* __restrict__ pm, const float* __restrict__ ps,
                            float* __restrict__ part, int n){
  float s = 0.f;
  for (int i = blockIdx.x*blockDim.x + threadIdx.x; i < n; i += gridDim.x*blockDim.x){
    float e = es[i], p = ps[i], d = em[i] - pm[i];
    s += 2.f*(logf(p) - logf(e)) + (e*e + d*d)/(p*p) - 1.f;
  }
  __shared__ float red[256];
  red[threadIdx.x] = s; __syncthreads();
  for (int off = 128; off; off >>= 1){
    if (threadIdx.x < off) red[threadIdx.x] += red[threadIdx.x + off];
    __syncthreads();
  }
  if (threadIdx.x == 0) part[blockIdx.x] = red[0];
}

__global__ void nll_partial(const float* __restrict__ y, const float* __restrict__ dm,
                            float* __restrict__ part, int n){
  float s = 0.f;
  for (int i = blockIdx.x*blockDim.x + threadIdx.x; i < n; i += gridDim.x*blockDim.x){
    float yy = y[i], d = dm[i];
    s += yy * logf(d) + (1.f - yy) * logf(1.f - d);
  }
  __shared__ float red[256];
  red[threadIdx.x] = s; __syncthreads();
  for (int off = 128; off; off >>= 1){
    if (threadIdx.x < off) red[threadIdx.x] += red[threadIdx.x + off];
    __syncthreads();
  }
  if (threadIdx.x == 0) part[blockIdx.x] = red[0];
}

__global__ void final_sum(const float* __restrict__ part, int n, float scale, float* __restrict__ out){
  float s = 0.f;
  for (int i = threadIdx.x; i < n; i += 256) s += part[i];
  __shared__ float red[256];
  red[threadIdx.x] = s; __syncthreads();
  for (int off = 128; off; off >>= 1){
    if (threadIdx.x < off) red[threadIdx.x] += red[threadIdx.x + off];
    __syncthreads();
  }
  if (threadIdx.x == 0) out[0] = scale * red[0];
}

// ---------------- host ----------------
extern "C" void kernel_launch(void* const* d_in, const int* in_sizes, int n_in,
                              void* d_out, int out_size, void* d_ws, size_t ws_size,
                              hipStream_t stream)
{
  const float* x   = (const float*)d_in[0];
  const float* y   = (const float*)d_in[1];
  const float* eps = (const float*)d_in[2];
  const float* enc_b1 = (const float*)d_in[8];
  const float* enc_b2 = (const float*)d_in[10];
  const float* encm_b = (const float*)d_in[12];
  const float* encs_b = (const float*)d_in[14];
  const float* pr_b   = (const float*)d_in[16];
  const float* prm_b  = (const float*)d_in[18];
  const float* prs_b  = (const float*)d_in[20];
  const float* dec_b1 = (const float*)d_in[22];
  const float* dec_b2 = (const float*)d_in[24];
  const float* decm_b = (const float*)d_in[26];
  const float* decs_b = (const float*)d_in[28];

  // ---- workspace layout (total ~164 MiB) ----
  char* ws = (char*)d_ws;
  size_t off = 0;
  auto alloc = [&](size_t bytes){ size_t o = off; off += (bytes + 255) & ~(size_t)255; return o; };
  const size_t o_big   = alloc((size_t)71303168);       // 68 MiB phase-union region
  const size_t o_hseq  = alloc((size_t)TBM * HD * 2);   // h_seq bf16 (32 MiB)
  const size_t o_aseq  = alloc((size_t)TBM * HD * 2);   // a_fwd bf16 (32 MiB)
  const size_t o_wbf   = alloc((size_t)16384000 * 2);   // all weights bf16 (~31.3 MiB)
  const size_t o_hst   = alloc((size_t)NB * HD * 4);    // f32 h carry between chunk launches
  const size_t o_bar   = alloc((size_t)1024);           // 4 barrier counters (256B apart)
  const size_t o_pkld  = alloc((size_t)1024 * 4);
  const size_t o_pnll  = alloc((size_t)1024 * 4);
  (void)off; (void)ws_size;

  char* big = ws + o_big;
  // phase A (GRUs): gi half-chunk [8192,3072] bf16 (48 MiB) + xbf + ybf
  unsigned short* gih = (unsigned short*)(big);
  unsigned short* xbf = (unsigned short*)(big + 50331648);
  unsigned short* ybf = (unsigned short*)(big + 54525952);
  // phase B (MLPs): tA (32 MiB) + tB (32 MiB) + zbf (4 MiB)
  unsigned short* tA  = (unsigned short*)(big);
  unsigned short* tB  = (unsigned short*)(big + 33554432);
  unsigned short* zbf = (unsigned short*)(big + 67108864);

  unsigned short* hseq = (unsigned short*)(ws + o_hseq);
  unsigned short* aseq = (unsigned short*)(ws + o_aseq);
  unsigned short* wbf  = (unsigned short*)(ws + o_wbf);
  float* hstate = (float*)(ws + o_hst);
  unsigned int* bar = (unsigned int*)(ws + o_bar);
  float* pkld = (float*)(ws + o_pkld);
  float* pnll = (float*)(ws + o_pnll);

  // weight bf16 sub-offsets (elements)
  const int   widx[15] = {3,4,5,6,7,9,11,13,15,17,19,21,23,25,27};
  const size_t wsz[15] = {393216,3145728,3538944,3145728,1048576,1048576,131072,131072,
                          1048576,131072,131072,1179648,1048576,131072,131072};
  size_t woff[15]; { size_t a = 0; for (int i = 0; i < 15; ++i){ woff[i] = a; a += wsz[i]; } }
  unsigned short* w_hWih = wbf + woff[0];
  unsigned short* w_hWhh = wbf + woff[1];
  unsigned short* w_aWih = wbf + woff[2];
  unsigned short* w_aWhh = wbf + woff[3];
  unsigned short* w_enc1 = wbf + woff[4];
  unsigned short* w_enc2 = wbf + woff[5];
  unsigned short* w_encm = wbf + woff[6];
  unsigned short* w_encs = wbf + woff[7];
  unsigned short* w_pr   = wbf + woff[8];
  unsigned short* w_prm  = wbf + woff[9];
  unsigned short* w_prs  = wbf + woff[10];
  unsigned short* w_dec1 = wbf + woff[11];
  unsigned short* w_dec2 = wbf + woff[12];
  unsigned short* w_decm = wbf + woff[13];
  unsigned short* w_decs = wbf + woff[14];

  float* out = (float*)d_out;
  float* em_out = out + 2;
  float* es_out = out + 2 + 2097152;
  float* dm_out = out + 2 + 2*2097152;   // doubles as pm scratch before decoder
  float* ds_out = out + 2 + 3*2097152;   // doubles as ps scratch before decoder
  float* pm = dm_out;
  float* ps = ds_out;

  // --- converts + barrier init ---
  cvt_bf16<<<256, 256, 0, stream>>>(x, xbf, TBM*XD);
  cvt_bf16<<<256, 256, 0, stream>>>(y, ybf, TBM*XD);
  for (int i = 0; i < 15; ++i)
    cvt_bf16<<<256, 256, 0, stream>>>((const float*)d_in[widx[i]], wbf + woff[i], (int)wsz[i]);
  hipMemsetAsync(bar, 0, 1024, stream);

  const dim3 blk(256);
  const dim3 gHalf3072(H3/128, 64);     // 8192 rows
  const dim3 g1024(HD/128, TBM/128);
  const dim3 g128(1, TBM/128);

  // --- GRU 1 (time-chunked gi: 2 x 128 steps; persistent column-parallel kernel) ---
  for (int c = 0; c < 2; ++c){
    gemm_bf16<0,1,0><<<gHalf3072, blk, 0, stream>>>(xbf, 0, XD, (const unsigned short*)nullptr, 0, XD,
                                                    w_hWih, nullptr, gih, H3, c*8192);
    gru_seq<<<64, 256, 0, stream>>>(w_hWhh, gih, hseq, hstate, bar + c*64,
                                    c*128, +1, 0, 128);
  }

  // --- GRU 2 (input [y_rev | h_rev], output written reversed => a_fwd) ---
  for (int c = 0; c < 2; ++c){
    gemm_bf16<0,1,0><<<gHalf3072, blk, 0, stream>>>(ybf, 1, XD, hseq, 1, XD + HD,
                                                    w_aWih, nullptr, gih, H3, c*8192);
    gru_seq<<<64, 256, 0, stream>>>(w_aWhh, gih, aseq, hstate, bar + (2 + c)*64,
                                    c*128, -1, 255, 128);
  }

  // --- encoder ---
  gemm_bf16<1,1,1><<<g1024, blk, 0, stream>>>(aseq, 0, HD, (const unsigned short*)nullptr, 0, HD,
                                              w_enc1, enc_b1, tA, HD, 0);
  gemm_bf16<1,1,1><<<g1024, blk, 0, stream>>>(tA, 0, HD, (const unsigned short*)nullptr, 0, HD,
                                              w_enc2, enc_b2, tB, HD, 0);
  gemm_bf16<0,0,1><<<g128, blk, 0, stream>>>(tB, 0, HD, (const unsigned short*)nullptr, 0, HD,
                                             w_encm, encm_b, em_out, ZD, 0);
  gemm_bf16<3,0,1><<<g128, blk, 0, stream>>>(tB, 0, HD, (const unsigned short*)nullptr, 0, HD,
                                             w_encs, encs_b, es_out, ZD, 0);
  z_make<<<2048, 256, 0, stream>>>(eps, em_out, es_out, zbf, TBM*ZD);

  // --- prior (pm/ps into dm/ds regions; kld BEFORE decoder overwrites them) ---
  gemm_bf16<1,1,1><<<g1024, blk, 0, stream>>>(hseq, 1, HD, (const unsigned short*)nullptr, 1, HD,
                                              w_pr, pr_b, tA, HD, 0);
  gemm_bf16<0,0,1><<<g128, blk, 0, stream>>>(tA, 0, HD, (const unsigned short*)nullptr, 0, HD,
                                             w_prm, prm_b, pm, ZD, 0);
  gemm_bf16<3,0,1><<<g128, blk, 0, stream>>>(tA, 0, HD, (const unsigned short*)nullptr, 0, HD,
                                             w_prs, prs_b, ps, ZD, 0);
  kld_partial<<<1024, 256, 0, stream>>>(em_out, es_out, pm, ps, pkld, TBM*ZD);
  final_sum<<<1, 256, 0, stream>>>(pkld, 1024, 0.5f, out + 0);

  // --- decoder ---
  gemm_bf16<1,1,1><<<g1024, blk, 0, stream>>>(zbf, 0, ZD, hseq, 1, ZD + HD,
                                              w_dec1, dec_b1, tA, HD, 0);
  gemm_bf16<1,1,1><<<g1024, blk, 0, stream>>>(tA, 0, HD, (const unsigned short*)nullptr, 0, HD,
                                              w_dec2, dec_b2, tB, HD, 0);
  gemm_bf16<2,0,1><<<g128, blk, 0, stream>>>(tB, 0, HD, (const unsigned short*)nullptr, 0, HD,
                                             w_decm, decm_b, dm_out, ZD, 0);
  gemm_bf16<3,0,1><<<g128, blk, 0, stream>>>(tB, 0, HD, (const unsigned short*)nullptr, 0, HD,
                                             w_decs, decs_b, ds_out, ZD, 0);

  // --- nll ---
  nll_partial<<<1024, 256, 0, stream>>>(y, dm_out, pnll, TBM*XD);
  final_sum<<<1, 256, 0, stream>>>(pnll, 1024, -1.0f, out + 1);
}

// Round 4
// 6838.107 us; speedup vs baseline: 2.8478x; 1.4853x over previous
//
#include <hip/hip_runtime.h>
#include <cstdint>
#include <cstddef>

// Problem dims
#define NT   256     // T
#define NB   64      // B
#define XD   128
#define HD   1024
#define ZD   128
#define H3   3072
#define TBM  16384   // T*B

typedef __attribute__((ext_vector_type(8))) short bf16x8;
typedef __attribute__((ext_vector_type(4))) float f32x4;

__device__ __forceinline__ unsigned short f2bf(float f){
  unsigned int u = __float_as_uint(f);
  u += 0x7fffu + ((u >> 16) & 1u);
  return (unsigned short)(u >> 16);
}
__device__ __forceinline__ float bf2f(unsigned short h){
  return __uint_as_float(((unsigned int)h) << 16);
}

// ---- coherent (L2-bypass) access helpers: sc0 sc1 go to the L3 coherence point ----
template<int OFF>
__device__ __forceinline__ uint4 ldg16_sc(const unsigned short* p){
  uint4 v;
  asm volatile("global_load_dwordx4 %0, %1, off offset:%2 sc0 sc1"
               : "=v"(v) : "v"(p), "i"(OFF) : "memory");
  return v;
}
__device__ __forceinline__ void st2_sc(unsigned short* p, unsigned int v){
  asm volatile("global_store_short %0, %1, off sc0 sc1" :: "v"(p), "v"(v) : "memory");
}
__device__ __forceinline__ void st4_sc(unsigned int* p, unsigned int v){
  asm volatile("global_store_dword %0, %1, off sc0 sc1" :: "v"(p), "v"(v) : "memory");
}
template<int N>
__device__ __forceinline__ void vwait(){
  asm volatile("s_waitcnt vmcnt(%0)" :: "i"(N) : "memory");
  __builtin_amdgcn_sched_barrier(0);
}
// each lane checks 4 slots; wave proceeds when all 256 slots >= target
__device__ __forceinline__ void wait_slots(const unsigned int* slots, unsigned int target){
  const unsigned int* p = slots + (threadIdx.x & 63) * 4;
  for (;;){
    uint4 v;
    asm volatile("global_load_dwordx4 %0, %1, off sc0 sc1\n\ts_waitcnt vmcnt(0)"
                 : "=v"(v) : "v"(p) : "memory");
    if (__all(v.x >= target && v.y >= target && v.z >= target && v.w >= target)) break;
    __builtin_amdgcn_s_sleep(1);
  }
  __builtin_amdgcn_sched_barrier(0);
}

// ---------------- convert f32 -> bf16 ----------------
__global__ void cvt_bf16(const float* __restrict__ src, unsigned short* __restrict__ dst, int n){
  for (int i = blockIdx.x*blockDim.x + threadIdx.x; i < n; i += gridDim.x*blockDim.x)
    dst[i] = f2bf(src[i]);
}

// ---------------- generic bf16 MFMA GEMM (unchanged) ----------------
template<int ACT, int OUT_BF, int BIAS>
__launch_bounds__(256)
__global__ void gemm_bf16(const unsigned short* __restrict__ A1, int rev1, int K1,
                          const unsigned short* __restrict__ A2, int rev2, int K,
                          const unsigned short* __restrict__ W,
                          const float* __restrict__ bias,
                          void* __restrict__ Cv, int N, int m0)
{
  __shared__ __align__(16) unsigned short As[128][40];
  __shared__ __align__(16) unsigned short Ws[128][40];
  const int tid   = threadIdx.x;
  const int mbase = blockIdx.y * 128;
  const int nbase = blockIdx.x * 128;
  const int wid = tid >> 6, lane = tid & 63;
  const int wr = wid >> 1, wc = wid & 1;
  const int fr = lane & 15;
  const int kc = (lane >> 4) * 8;
  const int K2 = K - K1;
  const int nk = K >> 5;

  f32x4 acc[4][4];
  #pragma unroll
  for (int i = 0; i < 4; ++i)
    #pragma unroll
    for (int j = 0; j < 4; ++j)
      acc[i][j] = (f32x4){0.f, 0.f, 0.f, 0.f};

  for (int ks = 0; ks < nk; ++ks){
    const int k0 = ks << 5;
    __syncthreads();
    for (int l = tid; l < 512; l += 256){
      int row = l >> 2, c = l & 3;
      int kk = k0 + c*8;
      int m = m0 + mbase + row;
      uint4 v;
      if (kk < K1){
        int mm = rev1 ? (((255 - (m >> 6)) << 6) | (m & 63)) : m;
        v = *(const uint4*)(A1 + (size_t)mm * K1 + kk);
      } else {
        int mm = rev2 ? (((255 - (m >> 6)) << 6) | (m & 63)) : m;
        v = *(const uint4*)(A2 + (size_t)mm * K2 + (kk - K1));
      }
      *(uint4*)&As[row][c*8] = v;
    }
    for (int l = tid; l < 512; l += 256){
      int row = l >> 2, c = l & 3;
      uint4 v = *(const uint4*)(W + (size_t)(nbase + row) * K + k0 + c*8);
      *(uint4*)&Ws[row][c*8] = v;
    }
    __syncthreads();
    bf16x8 af[4], bfm[4];
    #pragma unroll
    for (int f = 0; f < 4; ++f) af[f]  = *(const bf16x8*)&As[wr*64 + f*16 + fr][kc];
    #pragma unroll
    for (int f = 0; f < 4; ++f) bfm[f] = *(const bf16x8*)&Ws[wc*64 + f*16 + fr][kc];
    #pragma unroll
    for (int i = 0; i < 4; ++i)
      #pragma unroll
      for (int j = 0; j < 4; ++j)
        acc[i][j] = __builtin_amdgcn_mfma_f32_16x16x32_bf16(af[i], bfm[j], acc[i][j], 0, 0, 0);
  }

  #pragma unroll
  for (int i = 0; i < 4; ++i){
    #pragma unroll
    for (int j = 0; j < 4; ++j){
      #pragma unroll
      for (int r = 0; r < 4; ++r){
        int row = mbase + wr*64 + i*16 + (lane >> 4)*4 + r;
        int col = nbase + wc*64 + j*16 + fr;
        float v = acc[i][j][r];
        if (BIAS) v += bias[col];
        if (ACT == 1) v = fmaxf(v, 0.f);
        else if (ACT == 2) v = 1.f / (1.f + expf(-v));
        else if (ACT == 3) v = (v > 20.f) ? v : log1pf(expf(v));
        if (OUT_BF) ((unsigned short*)Cv)[(size_t)row * N + col] = f2bf(v);
        else        ((float*)Cv)[(size_t)row * N + col] = v;
      }
    }
  }
}

// ---------------- persistent GRU sequence kernel (v2: latency-optimized) ----------------
// 64 blocks x 256 threads. Block b owns output columns [16b,16b+16) of all 3 gates.
// W slice (3x16x1024 bf16 = 96KB) in LDS (MFMA B-fragment order), loaded once.
// h(t-1) A-fragments loaded straight from global via sc0sc1 (L3-coherent, no L2 staleness),
// software-pipelined in 4 batches of 8 with counted vmcnt.
// Barrier: per-(block,wave) slot array, sc0sc1 stores/polls. No fences, no atomics.
template<int KS0>
__device__ __forceinline__ void issue8(const unsigned short* hp, uint4* b){
  b[0] = ldg16_sc<(KS0+0)*64>(hp);
  b[1] = ldg16_sc<(KS0+1)*64>(hp);
  b[2] = ldg16_sc<(KS0+2)*64>(hp);
  b[3] = ldg16_sc<(KS0+3)*64>(hp);
  b[4] = ldg16_sc<(KS0+4)*64>(hp);
  b[5] = ldg16_sc<(KS0+5)*64>(hp);
  b[6] = ldg16_sc<(KS0+6)*64>(hp);
  b[7] = ldg16_sc<(KS0+7)*64>(hp);
}
__device__ __forceinline__ void compute8(int ks0, const uint4* b,
                                         const uint4 (*Wf)[3][64], int lane,
                                         f32x4& aR, f32x4& aZ, f32x4& aN){
  #pragma unroll
  for (int j = 0; j < 8; ++j){
    bf16x8 a = *(const bf16x8*)&b[j];
    int ks = ks0 + j;
    aR = __builtin_amdgcn_mfma_f32_16x16x32_bf16(a, *(const bf16x8*)&Wf[ks][0][lane], aR, 0, 0, 0);
    aZ = __builtin_amdgcn_mfma_f32_16x16x32_bf16(a, *(const bf16x8*)&Wf[ks][1][lane], aZ, 0, 0, 0);
    aN = __builtin_amdgcn_mfma_f32_16x16x32_bf16(a, *(const bf16x8*)&Wf[ks][2][lane], aN, 0, 0, 0);
  }
}

__global__ __launch_bounds__(256, 1)
void gru_seq(const unsigned short* __restrict__ W3,   // [3072][1024] bf16
             const unsigned short* __restrict__ gi,   // [nsteps][64][3072] bf16
             unsigned short* __restrict__ seq,        // [256][64][1024] bf16
             float* __restrict__ hstate,              // [64][1024] f32 carry
             unsigned int* __restrict__ slots,        // 256 u32, zeroed
             int t0, int dir, int out_off, int nsteps)
{
  __shared__ __align__(16) uint4 Wf[32][3][64];       // 96KB
  const int tid  = threadIdx.x;
  const int bid  = blockIdx.x;
  const int c0   = bid * 16;
  const int wid  = tid >> 6, lane = tid & 63;
  const int fr   = lane & 15, q = lane >> 4;
  const int rowb = wid*16 + q*4;                      // first of this thread's 4 C rows
  const int arow = wid*16 + fr;                       // this lane's A-fragment row

  for (int ks = wid*8; ks < wid*8 + 8; ++ks)
    #pragma unroll
    for (int g = 0; g < 3; ++g)
      Wf[ks][g][lane] = *(const uint4*)(W3 + (size_t)(g*HD + c0 + fr)*HD + ks*32 + q*8);

  float hc[4];
  if (t0 == 0){
    hc[0] = hc[1] = hc[2] = hc[3] = 0.f;
  } else {
    #pragma unroll
    for (int r = 0; r < 4; ++r)
      hc[r] = hstate[(size_t)(rowb + r)*HD + c0 + fr];
  }
  __syncthreads();

  for (int tt = 0; tt < nsteps; ++tt){
    const int t = t0 + tt;
    f32x4 aR = (f32x4){0.f,0.f,0.f,0.f};
    f32x4 aZ = (f32x4){0.f,0.f,0.f,0.f};
    f32x4 aN = (f32x4){0.f,0.f,0.f,0.f};

    if (t > 0){
      if (tt >= 1) wait_slots(slots, (unsigned int)tt);
      const unsigned short* hp = seq + (size_t)(out_off + dir*(t-1))*NB*HD
                                     + (size_t)arow*HD + q*8;
      uint4 A0[8], A1[8];
      issue8<0>(hp, A0);
      issue8<8>(hp, A1);
      vwait<8>();
      compute8(0, A0, Wf, lane, aR, aZ, aN);
      issue8<16>(hp, A0);
      vwait<8>();
      compute8(8, A1, Wf, lane, aR, aZ, aN);
      issue8<24>(hp, A1);
      vwait<8>();
      compute8(16, A0, Wf, lane, aR, aZ, aN);
      vwait<0>();
      compute8(24, A1, Wf, lane, aR, aZ, aN);
    }

    // gate inputs (L2-cached, read once)
    const unsigned short* gb = gi + (size_t)tt*NB*H3;
    float ir[4], iz[4], inn[4];
    #pragma unroll
    for (int r = 0; r < 4; ++r){
      const unsigned short* p = gb + (size_t)(rowb + r)*H3 + c0 + fr;
      ir[r]  = bf2f(p[0]);
      iz[r]  = bf2f(p[HD]);
      inn[r] = bf2f(p[2*HD]);
    }

    // gate math (fp32, in-register)
    unsigned short* so = seq + (size_t)(out_off + dir*t)*NB*HD + (size_t)rowb*HD + c0 + fr;
    #pragma unroll
    for (int r = 0; r < 4; ++r){
      float rr = 1.f / (1.f + expf(-(ir[r] + aR[r])));
      float zz = 1.f / (1.f + expf(-(iz[r] + aZ[r])));
      float nn = tanhf(inn[r] + rr * aN[r]);
      hc[r] = (1.f - zz) * nn + zz * hc[r];
      st2_sc(so + (size_t)r*HD, (unsigned int)f2bf(hc[r]));
    }
    if (tt < nsteps - 1){
      vwait<0>();                                   // all h stores visible at L3
      if (lane == 0) st4_sc((unsigned int*)slots + bid*4 + wid, (unsigned int)(tt + 1));
    }
  }

  #pragma unroll
  for (int r = 0; r < 4; ++r)
    hstate[(size_t)(rowb + r)*HD + c0 + fr] = hc[r];
}

// ---------------- z = eps*enc_std + enc_mean (bf16 out) ----------------
__global__ void z_make(const float* __restrict__ eps, const float* __restrict__ em,
                       const float* __restrict__ es, unsigned short* __restrict__ zb, int n){
  for (int i = blockIdx.x*blockDim.x + threadIdx.x; i < n; i += gridDim.x*blockDim.x)
    zb[i] = f2bf(eps[i] * es[i] + em[i]);
}

// ---------------- reductions ----------------
__global__ void kld_partial(const float* __restrict__ em, const float* __restrict__ es,
                            const float* __restrict__ pm, const float* __restrict__ ps,
                            float* __restrict__ part, int n){
  float s = 0.f;
  for (int i = blockIdx.x*blockDim.x + threadIdx.x; i < n; i += gridDim.x*blockDim.x){
    float e = es[i], p = ps[i], d = em[i] - pm[i];
    s += 2.f*(logf(p) - logf(e)) + (e*e + d*d)/(p*p) - 1.f;
  }
  __shared__ float red[256];
  red[threadIdx.x] = s; __syncthreads();
  for (int off = 128; off; off >>= 1){
    if (threadIdx.x < off) red[threadIdx.x] += red[threadIdx.x + off];
    __syncthreads();
  }
  if (threadIdx.x == 0) part[blockIdx.x] = red[0];
}

__global__ void nll_partial(const float* __restrict__ y, const float* __restrict__ dm,
                            float* __restrict__ part, int n){
  float s = 0.f;
  for (int i = blockIdx.x*blockDim.x + threadIdx.x; i < n; i += gridDim.x*blockDim.x){
    float yy = y[i], d = dm[i];
    s += yy * logf(d) + (1.f - yy) * logf(1.f - d);
  }
  __shared__ float red[256];
  red[threadIdx.x] = s; __syncthreads();
  for (int off = 128; off; off >>= 1){
    if (threadIdx.x < off) red[threadIdx.x] += red[threadIdx.x + off];
    __syncthreads();
  }
  if (threadIdx.x == 0) part[blockIdx.x] = red[0];
}

__global__ void final_sum(const float* __restrict__ part, int n, float scale, float* __restrict__ out){
  float s = 0.f;
  for (int i = threadIdx.x; i < n; i += 256) s += part[i];
  __shared__ float red[256];
  red[threadIdx.x] = s; __syncthreads();
  for (int off = 128; off; off >>= 1){
    if (threadIdx.x < off) red[threadIdx.x] += red[threadIdx.x + off];
    __syncthreads();
  }
  if (threadIdx.x == 0) out[0] = scale * red[0];
}

// ---------------- host ----------------
extern "C" void kernel_launch(void* const* d_in, const int* in_sizes, int n_in,
                              void* d_out, int out_size, void* d_ws, size_t ws_size,
                              hipStream_t stream)
{
  const float* x   = (const float*)d_in[0];
  const float* y   = (const float*)d_in[1];
  const float* eps = (const float*)d_in[2];
  const float* enc_b1 = (const float*)d_in[8];
  const float* enc_b2 = (const float*)d_in[10];
  const float* encm_b = (const float*)d_in[12];
  const float* encs_b = (const float*)d_in[14];
  const float* pr_b   = (const float*)d_in[16];
  const float* prm_b  = (const float*)d_in[18];
  const float* prs_b  = (const float*)d_in[20];
  const float* dec_b1 = (const float*)d_in[22];
  const float* dec_b2 = (const float*)d_in[24];
  const float* decm_b = (const float*)d_in[26];
  const float* decs_b = (const float*)d_in[28];

  // ---- workspace layout (total ~164 MiB) ----
  char* ws = (char*)d_ws;
  size_t off = 0;
  auto alloc = [&](size_t bytes){ size_t o = off; off += (bytes + 255) & ~(size_t)255; return o; };
  const size_t o_big   = alloc((size_t)71303168);       // 68 MiB phase-union region
  const size_t o_hseq  = alloc((size_t)TBM * HD * 2);   // h_seq bf16 (32 MiB)
  const size_t o_aseq  = alloc((size_t)TBM * HD * 2);   // a_fwd bf16 (32 MiB)
  const size_t o_wbf   = alloc((size_t)16384000 * 2);   // all weights bf16 (~31.3 MiB)
  const size_t o_hst   = alloc((size_t)NB * HD * 4);    // f32 h carry between chunk launches
  const size_t o_bar   = alloc((size_t)4096);           // 4 x 256 barrier slots
  const size_t o_pkld  = alloc((size_t)1024 * 4);
  const size_t o_pnll  = alloc((size_t)1024 * 4);
  (void)off; (void)ws_size;

  char* big = ws + o_big;
  unsigned short* gih = (unsigned short*)(big);
  unsigned short* xbf = (unsigned short*)(big + 50331648);
  unsigned short* ybf = (unsigned short*)(big + 54525952);
  unsigned short* tA  = (unsigned short*)(big);
  unsigned short* tB  = (unsigned short*)(big + 33554432);
  unsigned short* zbf = (unsigned short*)(big + 67108864);

  unsigned short* hseq = (unsigned short*)(ws + o_hseq);
  unsigned short* aseq = (unsigned short*)(ws + o_aseq);
  unsigned short* wbf  = (unsigned short*)(ws + o_wbf);
  float* hstate = (float*)(ws + o_hst);
  unsigned int* bar = (unsigned int*)(ws + o_bar);
  float* pkld = (float*)(ws + o_pkld);
  float* pnll = (float*)(ws + o_pnll);

  const int   widx[15] = {3,4,5,6,7,9,11,13,15,17,19,21,23,25,27};
  const size_t wsz[15] = {393216,3145728,3538944,3145728,1048576,1048576,131072,131072,
                          1048576,131072,131072,1179648,1048576,131072,131072};
  size_t woff[15]; { size_t a = 0; for (int i = 0; i < 15; ++i){ woff[i] = a; a += wsz[i]; } }
  unsigned short* w_hWih = wbf + woff[0];
  unsigned short* w_hWhh = wbf + woff[1];
  unsigned short* w_aWih = wbf + woff[2];
  unsigned short* w_aWhh = wbf + woff[3];
  unsigned short* w_enc1 = wbf + woff[4];
  unsigned short* w_enc2 = wbf + woff[5];
  unsigned short* w_encm = wbf + woff[6];
  unsigned short* w_encs = wbf + woff[7];
  unsigned short* w_pr   = wbf + woff[8];
  unsigned short* w_prm  = wbf + woff[9];
  unsigned short* w_prs  = wbf + woff[10];
  unsigned short* w_dec1 = wbf + woff[11];
  unsigned short* w_dec2 = wbf + woff[12];
  unsigned short* w_decm = wbf + woff[13];
  unsigned short* w_decs = wbf + woff[14];

  float* out = (float*)d_out;
  float* em_out = out + 2;
  float* es_out = out + 2 + 2097152;
  float* dm_out = out + 2 + 2*2097152;   // doubles as pm scratch before decoder
  float* ds_out = out + 2 + 3*2097152;   // doubles as ps scratch before decoder
  float* pm = dm_out;
  float* ps = ds_out;

  // --- converts + barrier init ---
  cvt_bf16<<<256, 256, 0, stream>>>(x, xbf, TBM*XD);
  cvt_bf16<<<256, 256, 0, stream>>>(y, ybf, TBM*XD);
  for (int i = 0; i < 15; ++i)
    cvt_bf16<<<256, 256, 0, stream>>>((const float*)d_in[widx[i]], wbf + woff[i], (int)wsz[i]);
  hipMemsetAsync(bar, 0, 4096, stream);

  const dim3 blk(256);
  const dim3 gHalf3072(H3/128, 64);     // 8192 rows
  const dim3 g1024(HD/128, TBM/128);
  const dim3 g128(1, TBM/128);

  // --- GRU 1 (time-chunked gi: 2 x 128 steps; persistent column-parallel kernel) ---
  for (int c = 0; c < 2; ++c){
    gemm_bf16<0,1,0><<<gHalf3072, blk, 0, stream>>>(xbf, 0, XD, (const unsigned short*)nullptr, 0, XD,
                                                    w_hWih, nullptr, gih, H3, c*8192);
    gru_seq<<<64, 256, 0, stream>>>(w_hWhh, gih, hseq, hstate, bar + c*256,
                                    c*128, +1, 0, 128);
  }

  // --- GRU 2 (input [y_rev | h_rev], output written reversed => a_fwd) ---
  for (int c = 0; c < 2; ++c){
    gemm_bf16<0,1,0><<<gHalf3072, blk, 0, stream>>>(ybf, 1, XD, hseq, 1, XD + HD,
                                                    w_aWih, nullptr, gih, H3, c*8192);
    gru_seq<<<64, 256, 0, stream>>>(w_aWhh, gih, aseq, hstate, bar + (2 + c)*256,
                                    c*128, -1, 255, 128);
  }

  // --- encoder ---
  gemm_bf16<1,1,1><<<g1024, blk, 0, stream>>>(aseq, 0, HD, (const unsigned short*)nullptr, 0, HD,
                                              w_enc1, enc_b1, tA, HD, 0);
  gemm_bf16<1,1,1><<<g1024, blk, 0, stream>>>(tA, 0, HD, (const unsigned short*)nullptr, 0, HD,
                                              w_enc2, enc_b2, tB, HD, 0);
  gemm_bf16<0,0,1><<<g128, blk, 0, stream>>>(tB, 0, HD, (const unsigned short*)nullptr, 0, HD,
                                             w_encm, encm_b, em_out, ZD, 0);
  gemm_bf16<3,0,1><<<g128, blk, 0, stream>>>(tB, 0, HD, (const unsigned short*)nullptr, 0, HD,
                                             w_encs, encs_b, es_out, ZD, 0);
  z_make<<<2048, 256, 0, stream>>>(eps, em_out, es_out, zbf, TBM*ZD);

  // --- prior (pm/ps into dm/ds regions; kld BEFORE decoder overwrites them) ---
  gemm_bf16<1,1,1><<<g1024, blk, 0, stream>>>(hseq, 1, HD, (const unsigned short*)nullptr, 1, HD,
                                              w_pr, pr_b, tA, HD, 0);
  gemm_bf16<0,0,1><<<g128, blk, 0, stream>>>(tA, 0, HD, (const unsigned short*)nullptr, 0, HD,
                                             w_prm, prm_b, pm, ZD, 0);
  gemm_bf16<3,0,1><<<g128, blk, 0, stream>>>(tA, 0, HD, (const unsigned short*)nullptr, 0, HD,
                                             w_prs, prs_b, ps, ZD, 0);
  kld_partial<<<1024, 256, 0, stream>>>(em_out, es_out, pm, ps, pkld, TBM*ZD);
  final_sum<<<1, 256, 0, stream>>>(pkld, 1024, 0.5f, out + 0);

  // --- decoder ---
  gemm_bf16<1,1,1><<<g1024, blk, 0, stream>>>(zbf, 0, ZD, hseq, 1, ZD + HD,
                                              w_dec1, dec_b1, tA, HD, 0);
  gemm_bf16<1,1,1><<<g1024, blk, 0, stream>>>(tA, 0, HD, (const unsigned short*)nullptr, 0, HD,
                                              w_dec2, dec_b2, tB, HD, 0);
  gemm_bf16<2,0,1><<<g128, blk, 0, stream>>>(tB, 0, HD, (const unsigned short*)nullptr, 0, HD,
                                             w_decm, decm_b, dm_out, ZD, 0);
  gemm_bf16<3,0,1><<<g128, blk, 0, stream>>>(tB, 0, HD, (const unsigned short*)nullptr, 0, HD,
                                             w_decs, decs_b, ds_out, ZD, 0);

  // --- nll ---
  nll_partial<<<1024, 256, 0, stream>>>(y, dm_out, pnll, TBM*XD);
  final_sum<<<1, 256, 0, stream>>>(pnll, 1024, -1.0f, out + 1);
}

// Round 5
// 5385.534 us; speedup vs baseline: 3.6160x; 1.2697x over previous
//
#include <hip/hip_runtime.h>
#include <cstdint>
#include <cstddef>

// Problem dims
#define NT   256     // T
#define NB   64      // B
#define XD   128
#define HD   1024
#define ZD   128
#define H3   3072
#define TBM  16384   // T*B

typedef __attribute__((ext_vector_type(8))) short bf16x8;
typedef __attribute__((ext_vector_type(4))) float f32x4;

__device__ __forceinline__ unsigned short f2bf(float f){
  unsigned int u = __float_as_uint(f);
  u += 0x7fffu + ((u >> 16) & 1u);
  return (unsigned short)(u >> 16);
}
__device__ __forceinline__ float bf2f(unsigned short h){
  return __uint_as_float(((unsigned int)h) << 16);
}

// ---- coherent (L2-bypass) store helpers: sc0 sc1 write through to the L3 coherence point ----
__device__ __forceinline__ void st2_sc(unsigned short* p, unsigned int v){
  asm volatile("global_store_short %0, %1, off sc0 sc1" :: "v"(p), "v"(v) : "memory");
}
__device__ __forceinline__ void st4_sc(unsigned int* p, unsigned int v){
  asm volatile("global_store_dword %0, %1, off sc0 sc1" :: "v"(p), "v"(v) : "memory");
}
template<int N>
__device__ __forceinline__ void vwait(){
  asm volatile("s_waitcnt vmcnt(%0)" :: "i"(N) : "memory");
  __builtin_amdgcn_sched_barrier(0);
}

// fast gates
__device__ __forceinline__ float fsigmoid(float x){
  return 1.f / (1.f + __expf(-x));
}
__device__ __forceinline__ float ftanh(float x){
  float xc = fminf(fmaxf(x, -15.f), 15.f);
  float e = __expf(2.f * xc);
  return (e - 1.f) / (e + 1.f);
}

// wave0 polls 64 spread tags (128B apart, sc0sc1 = L2-bypass); other waves park at barrier.
__device__ __forceinline__ void wait_tags(const unsigned int* tags, unsigned int target){
  if (threadIdx.x < 64){
    const unsigned int* p = tags + threadIdx.x * 32;   // 128B spacing
    for (;;){
      unsigned int v;
      asm volatile("global_load_dword %0, %1, off sc0 sc1\n\ts_waitcnt vmcnt(0)"
                   : "=v"(v) : "v"(p) : "memory");
      if (__all((int)(v >= target))) break;
      __builtin_amdgcn_s_sleep(4);
    }
  }
  __syncthreads();
}

// ---------------- convert f32 -> bf16 ----------------
__global__ void cvt_bf16(const float* __restrict__ src, unsigned short* __restrict__ dst, int n){
  for (int i = blockIdx.x*blockDim.x + threadIdx.x; i < n; i += gridDim.x*blockDim.x)
    dst[i] = f2bf(src[i]);
}

// ---------------- generic bf16 MFMA GEMM (unchanged) ----------------
template<int ACT, int OUT_BF, int BIAS>
__launch_bounds__(256)
__global__ void gemm_bf16(const unsigned short* __restrict__ A1, int rev1, int K1,
                          const unsigned short* __restrict__ A2, int rev2, int K,
                          const unsigned short* __restrict__ W,
                          const float* __restrict__ bias,
                          void* __restrict__ Cv, int N, int m0)
{
  __shared__ __align__(16) unsigned short As[128][40];
  __shared__ __align__(16) unsigned short Ws[128][40];
  const int tid   = threadIdx.x;
  const int mbase = blockIdx.y * 128;
  const int nbase = blockIdx.x * 128;
  const int wid = tid >> 6, lane = tid & 63;
  const int wr = wid >> 1, wc = wid & 1;
  const int fr = lane & 15;
  const int kc = (lane >> 4) * 8;
  const int K2 = K - K1;
  const int nk = K >> 5;

  f32x4 acc[4][4];
  #pragma unroll
  for (int i = 0; i < 4; ++i)
    #pragma unroll
    for (int j = 0; j < 4; ++j)
      acc[i][j] = (f32x4){0.f, 0.f, 0.f, 0.f};

  for (int ks = 0; ks < nk; ++ks){
    const int k0 = ks << 5;
    __syncthreads();
    for (int l = tid; l < 512; l += 256){
      int row = l >> 2, c = l & 3;
      int kk = k0 + c*8;
      int m = m0 + mbase + row;
      uint4 v;
      if (kk < K1){
        int mm = rev1 ? (((255 - (m >> 6)) << 6) | (m & 63)) : m;
        v = *(const uint4*)(A1 + (size_t)mm * K1 + kk);
      } else {
        int mm = rev2 ? (((255 - (m >> 6)) << 6) | (m & 63)) : m;
        v = *(const uint4*)(A2 + (size_t)mm * K2 + (kk - K1));
      }
      *(uint4*)&As[row][c*8] = v;
    }
    for (int l = tid; l < 512; l += 256){
      int row = l >> 2, c = l & 3;
      uint4 v = *(const uint4*)(W + (size_t)(nbase + row) * K + k0 + c*8);
      *(uint4*)&Ws[row][c*8] = v;
    }
    __syncthreads();
    bf16x8 af[4], bfm[4];
    #pragma unroll
    for (int f = 0; f < 4; ++f) af[f]  = *(const bf16x8*)&As[wr*64 + f*16 + fr][kc];
    #pragma unroll
    for (int f = 0; f < 4; ++f) bfm[f] = *(const bf16x8*)&Ws[wc*64 + f*16 + fr][kc];
    #pragma unroll
    for (int i = 0; i < 4; ++i)
      #pragma unroll
      for (int j = 0; j < 4; ++j)
        acc[i][j] = __builtin_amdgcn_mfma_f32_16x16x32_bf16(af[i], bfm[j], acc[i][j], 0, 0, 0);
  }

  #pragma unroll
  for (int i = 0; i < 4; ++i){
    #pragma unroll
    for (int j = 0; j < 4; ++j){
      #pragma unroll
      for (int r = 0; r < 4; ++r){
        int row = mbase + wr*64 + i*16 + (lane >> 4)*4 + r;
        int col = nbase + wc*64 + j*16 + fr;
        float v = acc[i][j][r];
        if (BIAS) v += bias[col];
        if (ACT == 1) v = fmaxf(v, 0.f);
        else if (ACT == 2) v = 1.f / (1.f + expf(-v));
        else if (ACT == 3) v = (v > 20.f) ? v : log1pf(expf(v));
        if (OUT_BF) ((unsigned short*)Cv)[(size_t)row * N + col] = f2bf(v);
        else        ((float*)Cv)[(size_t)row * N + col] = v;
      }
    }
  }
}

// ---------------- persistent GRU sequence kernel (v3) ----------------
// 64 blocks x 256 threads. Block b owns output columns [16b,16b+16) of all 3 gates.
// W slice (3x16x1024 bf16 = 96KB) in LDS (MFMA B-fragment order), loaded once.
// h(t-1): PLAIN cacheable loads (first-touch per line; 8 blocks/XCD share L2 copies).
// h stores: sc0sc1 write-through (land at L3 so other XCDs see them).
// Barrier: 1 tag per block in its own 128B sector; wave0-only poll with backoff.
__global__ __launch_bounds__(256, 1)
void gru_seq(const unsigned short* __restrict__ W3,   // [3072][1024] bf16
             const unsigned short* __restrict__ gi,   // [nsteps][64][3072] bf16
             unsigned short* __restrict__ seq,        // [256][64][1024] bf16
             float* __restrict__ hstate,              // [64][1024] f32 carry
             unsigned int* __restrict__ tags,         // 64 tags, 128B apart, zeroed
             int t0, int dir, int out_off, int nsteps)
{
  __shared__ __align__(16) uint4 Wf[32][3][64];       // 96KB
  const int tid  = threadIdx.x;
  const int bid  = blockIdx.x;
  const int c0   = bid * 16;
  const int wid  = tid >> 6, lane = tid & 63;
  const int fr   = lane & 15, q = lane >> 4;
  const int rowb = wid*16 + q*4;                      // first of this thread's 4 C rows
  const int arow = wid*16 + fr;                       // this lane's A-fragment row

  for (int ks = wid*8; ks < wid*8 + 8; ++ks)
    #pragma unroll
    for (int g = 0; g < 3; ++g)
      Wf[ks][g][lane] = *(const uint4*)(W3 + (size_t)(g*HD + c0 + fr)*HD + ks*32 + q*8);

  float hc[4];
  if (t0 == 0){
    hc[0] = hc[1] = hc[2] = hc[3] = 0.f;
  } else {
    #pragma unroll
    for (int r = 0; r < 4; ++r)
      hc[r] = hstate[(size_t)(rowb + r)*HD + c0 + fr];
  }
  __syncthreads();

  for (int tt = 0; tt < nsteps; ++tt){
    const int t = t0 + tt;

    // gate inputs for THIS step: issue early (plain loads, overlap the tag poll)
    unsigned short g_ir[4], g_iz[4], g_in[4];
    {
      const unsigned short* gb = gi + (size_t)tt*NB*H3;
      #pragma unroll
      for (int r = 0; r < 4; ++r){
        const unsigned short* p = gb + (size_t)(rowb + r)*H3 + c0 + fr;
        g_ir[r] = p[0];
        g_iz[r] = p[HD];
        g_in[r] = p[2*HD];
      }
    }

    f32x4 aR = (f32x4){0.f,0.f,0.f,0.f};
    f32x4 aZ = (f32x4){0.f,0.f,0.f,0.f};
    f32x4 aN = (f32x4){0.f,0.f,0.f,0.f};

    if (t > 0){
      if (tt >= 1) wait_tags(tags, (unsigned int)tt);
      const unsigned short* hp = seq + (size_t)(out_off + dir*(t-1))*NB*HD
                                     + (size_t)arow*HD + q*8;
      uint4 A[32];
      #pragma unroll
      for (int ks = 0; ks < 32; ++ks)
        A[ks] = *(const uint4*)(hp + ks*32);
      #pragma unroll
      for (int ks = 0; ks < 32; ++ks){
        bf16x8 a = *(const bf16x8*)&A[ks];
        aR = __builtin_amdgcn_mfma_f32_16x16x32_bf16(a, *(const bf16x8*)&Wf[ks][0][lane], aR, 0, 0, 0);
        aZ = __builtin_amdgcn_mfma_f32_16x16x32_bf16(a, *(const bf16x8*)&Wf[ks][1][lane], aZ, 0, 0, 0);
        aN = __builtin_amdgcn_mfma_f32_16x16x32_bf16(a, *(const bf16x8*)&Wf[ks][2][lane], aN, 0, 0, 0);
      }
    }

    // gate math (fp32, in-register)
    unsigned short* so = seq + (size_t)(out_off + dir*t)*NB*HD + (size_t)rowb*HD + c0 + fr;
    #pragma unroll
    for (int r = 0; r < 4; ++r){
      float rr = fsigmoid(bf2f(g_ir[r]) + aR[r]);
      float zz = fsigmoid(bf2f(g_iz[r]) + aZ[r]);
      float nn = ftanh(bf2f(g_in[r]) + rr * aN[r]);
      hc[r] = (1.f - zz) * nn + zz * hc[r];
      st2_sc(so + (size_t)r*HD, (unsigned int)f2bf(hc[r]));
    }
    if (tt < nsteps - 1){
      vwait<0>();                 // own stores acked at coherence point
      __syncthreads();            // all waves' stores acked
      if (tid == 0) st4_sc(tags + bid*32, (unsigned int)(tt + 1));
    }
  }

  #pragma unroll
  for (int r = 0; r < 4; ++r)
    hstate[(size_t)(rowb + r)*HD + c0 + fr] = hc[r];
}

// ---------------- z = eps*enc_std + enc_mean (bf16 out) ----------------
__global__ void z_make(const float* __restrict__ eps, const float* __restrict__ em,
                       const float* __restrict__ es, unsigned short* __restrict__ zb, int n){
  for (int i = blockIdx.x*blockDim.x + threadIdx.x; i < n; i += gridDim.x*blockDim.x)
    zb[i] = f2bf(eps[i] * es[i] + em[i]);
}

// ---------------- reductions ----------------
__global__ void kld_partial(const float* __restrict__ em, const float* __restrict__ es,
                            const float* __restrict__ pm, const float* __restrict__ ps,
                            float* __restrict__ part, int n){
  float s = 0.f;
  for (int i = blockIdx.x*blockDim.x + threadIdx.x; i < n; i += gridDim.x*blockDim.x){
    float e = es[i], p = ps[i], d = em[i] - pm[i];
    s += 2.f*(logf(p) - logf(e)) + (e*e + d*d)/(p*p) - 1.f;
  }
  __shared__ float red[256];
  red[threadIdx.x] = s; __syncthreads();
  for (int off = 128; off; off >>= 1){
    if (threadIdx.x < off) red[threadIdx.x] += red[threadIdx.x + off];
    __syncthreads();
  }
  if (threadIdx.x == 0) part[blockIdx.x] = red[0];
}

__global__ void nll_partial(const float* __restrict__ y, const float* __restrict__ dm,
                            float* __restrict__ part, int n){
  float s = 0.f;
  for (int i = blockIdx.x*blockDim.x + threadIdx.x; i < n; i += gridDim.x*blockDim.x){
    float yy = y[i], d = dm[i];
    s += yy * logf(d) + (1.f - yy) * logf(1.f - d);
  }
  __shared__ float red[256];
  red[threadIdx.x] = s; __syncthreads();
  for (int off = 128; off; off >>= 1){
    if (threadIdx.x < off) red[threadIdx.x] += red[threadIdx.x + off];
    __syncthreads();
  }
  if (threadIdx.x == 0) part[blockIdx.x] = red[0];
}

__global__ void final_sum(const float* __restrict__ part, int n, float scale, float* __restrict__ out){
  float s = 0.f;
  for (int i = threadIdx.x; i < n; i += 256) s += part[i];
  __shared__ float red[256];
  red[threadIdx.x] = s; __syncthreads();
  for (int off = 128; off; off >>= 1){
    if (threadIdx.x < off) red[threadIdx.x] += red[threadIdx.x + off];
    __syncthreads();
  }
  if (threadIdx.x == 0) out[0] = scale * red[0];
}

// ---------------- host ----------------
extern "C" void kernel_launch(void* const* d_in, const int* in_sizes, int n_in,
                              void* d_out, int out_size, void* d_ws, size_t ws_size,
                              hipStream_t stream)
{
  const float* x   = (const float*)d_in[0];
  const float* y   = (const float*)d_in[1];
  const float* eps = (const float*)d_in[2];
  const float* enc_b1 = (const float*)d_in[8];
  const float* enc_b2 = (const float*)d_in[10];
  const float* encm_b = (const float*)d_in[12];
  const float* encs_b = (const float*)d_in[14];
  const float* pr_b   = (const float*)d_in[16];
  const float* prm_b  = (const float*)d_in[18];
  const float* prs_b  = (const float*)d_in[20];
  const float* dec_b1 = (const float*)d_in[22];
  const float* dec_b2 = (const float*)d_in[24];
  const float* decm_b = (const float*)d_in[26];
  const float* decs_b = (const float*)d_in[28];

  // ---- workspace layout (total ~164 MiB) ----
  char* ws = (char*)d_ws;
  size_t off = 0;
  auto alloc = [&](size_t bytes){ size_t o = off; off += (bytes + 255) & ~(size_t)255; return o; };
  const size_t o_big   = alloc((size_t)71303168);       // 68 MiB phase-union region
  const size_t o_hseq  = alloc((size_t)TBM * HD * 2);   // h_seq bf16 (32 MiB)
  const size_t o_aseq  = alloc((size_t)TBM * HD * 2);   // a_fwd bf16 (32 MiB)
  const size_t o_wbf   = alloc((size_t)16384000 * 2);   // all weights bf16 (~31.3 MiB)
  const size_t o_hst   = alloc((size_t)NB * HD * 4);    // f32 h carry between chunk launches
  const size_t o_bar   = alloc((size_t)32768);          // 4 x 64 tags (128B apart)
  const size_t o_pkld  = alloc((size_t)1024 * 4);
  const size_t o_pnll  = alloc((size_t)1024 * 4);
  (void)off; (void)ws_size;

  char* big = ws + o_big;
  unsigned short* gih = (unsigned short*)(big);
  unsigned short* xbf = (unsigned short*)(big + 50331648);
  unsigned short* ybf = (unsigned short*)(big + 54525952);
  unsigned short* tA  = (unsigned short*)(big);
  unsigned short* tB  = (unsigned short*)(big + 33554432);
  unsigned short* zbf = (unsigned short*)(big + 67108864);

  unsigned short* hseq = (unsigned short*)(ws + o_hseq);
  unsigned short* aseq = (unsigned short*)(ws + o_aseq);
  unsigned short* wbf  = (unsigned short*)(ws + o_wbf);
  float* hstate = (float*)(ws + o_hst);
  unsigned int* bar = (unsigned int*)(ws + o_bar);
  float* pkld = (float*)(ws + o_pkld);
  float* pnll = (float*)(ws + o_pnll);

  const int   widx[15] = {3,4,5,6,7,9,11,13,15,17,19,21,23,25,27};
  const size_t wsz[15] = {393216,3145728,3538944,3145728,1048576,1048576,131072,131072,
                          1048576,131072,131072,1179648,1048576,131072,131072};
  size_t woff[15]; { size_t a = 0; for (int i = 0; i < 15; ++i){ woff[i] = a; a += wsz[i]; } }
  unsigned short* w_hWih = wbf + woff[0];
  unsigned short* w_hWhh = wbf + woff[1];
  unsigned short* w_aWih = wbf + woff[2];
  unsigned short* w_aWhh = wbf + woff[3];
  unsigned short* w_enc1 = wbf + woff[4];
  unsigned short* w_enc2 = wbf + woff[5];
  unsigned short* w_encm = wbf + woff[6];
  unsigned short* w_encs = wbf + woff[7];
  unsigned short* w_pr   = wbf + woff[8];
  unsigned short* w_prm  = wbf + woff[9];
  unsigned short* w_prs  = wbf + woff[10];
  unsigned short* w_dec1 = wbf + woff[11];
  unsigned short* w_dec2 = wbf + woff[12];
  unsigned short* w_decm = wbf + woff[13];
  unsigned short* w_decs = wbf + woff[14];

  float* out = (float*)d_out;
  float* em_out = out + 2;
  float* es_out = out + 2 + 2097152;
  float* dm_out = out + 2 + 2*2097152;   // doubles as pm scratch before decoder
  float* ds_out = out + 2 + 3*2097152;   // doubles as ps scratch before decoder
  float* pm = dm_out;
  float* ps = ds_out;

  // --- converts + tag init ---
  cvt_bf16<<<256, 256, 0, stream>>>(x, xbf, TBM*XD);
  cvt_bf16<<<256, 256, 0, stream>>>(y, ybf, TBM*XD);
  for (int i = 0; i < 15; ++i)
    cvt_bf16<<<256, 256, 0, stream>>>((const float*)d_in[widx[i]], wbf + woff[i], (int)wsz[i]);
  hipMemsetAsync(bar, 0, 32768, stream);

  const dim3 blk(256);
  const dim3 gHalf3072(H3/128, 64);     // 8192 rows
  const dim3 g1024(HD/128, TBM/128);
  const dim3 g128(1, TBM/128);

  // --- GRU 1 (time-chunked gi: 2 x 128 steps; persistent column-parallel kernel) ---
  for (int c = 0; c < 2; ++c){
    gemm_bf16<0,1,0><<<gHalf3072, blk, 0, stream>>>(xbf, 0, XD, (const unsigned short*)nullptr, 0, XD,
                                                    w_hWih, nullptr, gih, H3, c*8192);
    gru_seq<<<64, 256, 0, stream>>>(w_hWhh, gih, hseq, hstate, bar + c*2048,
                                    c*128, +1, 0, 128);
  }

  // --- GRU 2 (input [y_rev | h_rev], output written reversed => a_fwd) ---
  for (int c = 0; c < 2; ++c){
    gemm_bf16<0,1,0><<<gHalf3072, blk, 0, stream>>>(ybf, 1, XD, hseq, 1, XD + HD,
                                                    w_aWih, nullptr, gih, H3, c*8192);
    gru_seq<<<64, 256, 0, stream>>>(w_aWhh, gih, aseq, hstate, bar + (2 + c)*2048,
                                    c*128, -1, 255, 128);
  }

  // --- encoder ---
  gemm_bf16<1,1,1><<<g1024, blk, 0, stream>>>(aseq, 0, HD, (const unsigned short*)nullptr, 0, HD,
                                              w_enc1, enc_b1, tA, HD, 0);
  gemm_bf16<1,1,1><<<g1024, blk, 0, stream>>>(tA, 0, HD, (const unsigned short*)nullptr, 0, HD,
                                              w_enc2, enc_b2, tB, HD, 0);
  gemm_bf16<0,0,1><<<g128, blk, 0, stream>>>(tB, 0, HD, (const unsigned short*)nullptr, 0, HD,
                                             w_encm, encm_b, em_out, ZD, 0);
  gemm_bf16<3,0,1><<<g128, blk, 0, stream>>>(tB, 0, HD, (const unsigned short*)nullptr, 0, HD,
                                             w_encs, encs_b, es_out, ZD, 0);
  z_make<<<2048, 256, 0, stream>>>(eps, em_out, es_out, zbf, TBM*ZD);

  // --- prior (pm/ps into dm/ds regions; kld BEFORE decoder overwrites them) ---
  gemm_bf16<1,1,1><<<g1024, blk, 0, stream>>>(hseq, 1, HD, (const unsigned short*)nullptr, 1, HD,
                                              w_pr, pr_b, tA, HD, 0);
  gemm_bf16<0,0,1><<<g128, blk, 0, stream>>>(tA, 0, HD, (const unsigned short*)nullptr, 0, HD,
                                             w_prm, prm_b, pm, ZD, 0);
  gemm_bf16<3,0,1><<<g128, blk, 0, stream>>>(tA, 0, HD, (const unsigned short*)nullptr, 0, HD,
                                             w_prs, prs_b, ps, ZD, 0);
  kld_partial<<<1024, 256, 0, stream>>>(em_out, es_out, pm, ps, pkld, TBM*ZD);
  final_sum<<<1, 256, 0, stream>>>(pkld, 1024, 0.5f, out + 0);

  // --- decoder ---
  gemm_bf16<1,1,1><<<g1024, blk, 0, stream>>>(zbf, 0, ZD, hseq, 1, ZD + HD,
                                              w_dec1, dec_b1, tA, HD, 0);
  gemm_bf16<1,1,1><<<g1024, blk, 0, stream>>>(tA, 0, HD, (const unsigned short*)nullptr, 0, HD,
                                              w_dec2, dec_b2, tB, HD, 0);
  gemm_bf16<2,0,1><<<g128, blk, 0, stream>>>(tB, 0, HD, (const unsigned short*)nullptr, 0, HD,
                                             w_decm, decm_b, dm_out, ZD, 0);
  gemm_bf16<3,0,1><<<g128, blk, 0, stream>>>(tB, 0, HD, (const unsigned short*)nullptr, 0, HD,
                                             w_decs, decs_b, ds_out, ZD, 0);

  // --- nll ---
  nll_partial<<<1024, 256, 0, stream>>>(y, dm_out, pnll, TBM*XD);
  final_sum<<<1, 256, 0, stream>>>(pnll, 1024, -1.0f, out + 1);
}

// Round 7
// 5302.990 us; speedup vs baseline: 3.6722x; 1.0156x over previous
//
#include <hip/hip_runtime.h>
#include <cstdint>
#include <cstddef>

// Problem dims
#define NT   256     // T
#define NB   64      // B
#define XD   128
#define HD   1024
#define ZD   128
#define H3   3072
#define TBM  16384   // T*B

typedef __attribute__((ext_vector_type(8))) short bf16x8;
typedef __attribute__((ext_vector_type(4))) float f32x4;
typedef __attribute__((ext_vector_type(4))) unsigned int u32x4;

__device__ __forceinline__ unsigned short f2bf(float f){
  unsigned int u = __float_as_uint(f);
  u += 0x7fffu + ((u >> 16) & 1u);
  return (unsigned short)(u >> 16);
}
__device__ __forceinline__ float bf2f(unsigned short h){
  return __uint_as_float(((unsigned int)h) << 16);
}

// ---- coherent (L2-bypass) store helpers: sc0 sc1 write through to the L3 coherence point ----
__device__ __forceinline__ void st16_sc(unsigned short* p, u32x4 v){
  asm volatile("global_store_dwordx4 %0, %1, off sc0 sc1" :: "v"(p), "v"(v) : "memory");
}
__device__ __forceinline__ void st4_sc(unsigned int* p, unsigned int v){
  asm volatile("global_store_dword %0, %1, off sc0 sc1" :: "v"(p), "v"(v) : "memory");
}
template<int N>
__device__ __forceinline__ void vwait(){
  asm volatile("s_waitcnt vmcnt(%0)" :: "i"(N) : "memory");
  __builtin_amdgcn_sched_barrier(0);
}

// fast gates
__device__ __forceinline__ float fsigmoid(float x){
  return 1.f / (1.f + __expf(-x));
}
__device__ __forceinline__ float ftanh(float x){
  float xc = fminf(fmaxf(x, -15.f), 15.f);
  float e = __expf(2.f * xc);
  return (e - 1.f) / (e + 1.f);
}

// wave0 polls 64 spread tags (128B apart, sc0sc1 = L2-bypass); other waves park at barrier.
__device__ __forceinline__ void wait_tags(const unsigned int* tags, unsigned int target){
  if (threadIdx.x < 64){
    const unsigned int* p = tags + threadIdx.x * 32;   // 128B spacing
    for (;;){
      unsigned int v;
      asm volatile("global_load_dword %0, %1, off sc0 sc1\n\ts_waitcnt vmcnt(0)"
                   : "=v"(v) : "v"(p) : "memory");
      if (__all((int)(v >= target))) break;
      __builtin_amdgcn_s_sleep(2);
    }
  }
  __syncthreads();
}

// ---------------- convert f32 -> bf16 ----------------
__global__ void cvt_bf16(const float* __restrict__ src, unsigned short* __restrict__ dst, int n){
  for (int i = blockIdx.x*blockDim.x + threadIdx.x; i < n; i += gridDim.x*blockDim.x)
    dst[i] = f2bf(src[i]);
}

// ---------------- generic bf16 MFMA GEMM (unchanged) ----------------
template<int ACT, int OUT_BF, int BIAS>
__launch_bounds__(256)
__global__ void gemm_bf16(const unsigned short* __restrict__ A1, int rev1, int K1,
                          const unsigned short* __restrict__ A2, int rev2, int K,
                          const unsigned short* __restrict__ W,
                          const float* __restrict__ bias,
                          void* __restrict__ Cv, int N, int m0)
{
  __shared__ __align__(16) unsigned short As[128][40];
  __shared__ __align__(16) unsigned short Ws[128][40];
  const int tid   = threadIdx.x;
  const int mbase = blockIdx.y * 128;
  const int nbase = blockIdx.x * 128;
  const int wid = tid >> 6, lane = tid & 63;
  const int wr = wid >> 1, wc = wid & 1;
  const int fr = lane & 15;
  const int kc = (lane >> 4) * 8;
  const int K2 = K - K1;
  const int nk = K >> 5;

  f32x4 acc[4][4];
  #pragma unroll
  for (int i = 0; i < 4; ++i)
    #pragma unroll
    for (int j = 0; j < 4; ++j)
      acc[i][j] = (f32x4){0.f, 0.f, 0.f, 0.f};

  for (int ks = 0; ks < nk; ++ks){
    const int k0 = ks << 5;
    __syncthreads();
    for (int l = tid; l < 512; l += 256){
      int row = l >> 2, c = l & 3;
      int kk = k0 + c*8;
      int m = m0 + mbase + row;
      uint4 v;
      if (kk < K1){
        int mm = rev1 ? (((255 - (m >> 6)) << 6) | (m & 63)) : m;
        v = *(const uint4*)(A1 + (size_t)mm * K1 + kk);
      } else {
        int mm = rev2 ? (((255 - (m >> 6)) << 6) | (m & 63)) : m;
        v = *(const uint4*)(A2 + (size_t)mm * K2 + (kk - K1));
      }
      *(uint4*)&As[row][c*8] = v;
    }
    for (int l = tid; l < 512; l += 256){
      int row = l >> 2, c = l & 3;
      uint4 v = *(const uint4*)(W + (size_t)(nbase + row) * K + k0 + c*8);
      *(uint4*)&Ws[row][c*8] = v;
    }
    __syncthreads();
    bf16x8 af[4], bfm[4];
    #pragma unroll
    for (int f = 0; f < 4; ++f) af[f]  = *(const bf16x8*)&As[wr*64 + f*16 + fr][kc];
    #pragma unroll
    for (int f = 0; f < 4; ++f) bfm[f] = *(const bf16x8*)&Ws[wc*64 + f*16 + fr][kc];
    #pragma unroll
    for (int i = 0; i < 4; ++i)
      #pragma unroll
      for (int j = 0; j < 4; ++j)
        acc[i][j] = __builtin_amdgcn_mfma_f32_16x16x32_bf16(af[i], bfm[j], acc[i][j], 0, 0, 0);
  }

  #pragma unroll
  for (int i = 0; i < 4; ++i){
    #pragma unroll
    for (int j = 0; j < 4; ++j){
      #pragma unroll
      for (int r = 0; r < 4; ++r){
        int row = mbase + wr*64 + i*16 + (lane >> 4)*4 + r;
        int col = nbase + wc*64 + j*16 + fr;
        float v = acc[i][j][r];
        if (BIAS) v += bias[col];
        if (ACT == 1) v = fmaxf(v, 0.f);
        else if (ACT == 2) v = 1.f / (1.f + expf(-v));
        else if (ACT == 3) v = (v > 20.f) ? v : log1pf(expf(v));
        if (OUT_BF) ((unsigned short*)Cv)[(size_t)row * N + col] = f2bf(v);
        else        ((float*)Cv)[(size_t)row * N + col] = v;
      }
    }
  }
}

// ---------------- persistent GRU sequence kernel (v4) ----------------
// 64 blocks x 256 threads. Block b owns output columns [16b,16b+16) of all 3 gates.
// W slice (3x16x1024 bf16 = 96KB) in LDS (MFMA B-fragment order), loaded once.
// h(t-1): plain cacheable loads (first-touch per line; 8 blocks/XCD share L2 copies).
// h(t) write path: gate outputs -> 2KB LDS transpose -> 128 x 16B sc0sc1 stores
//   (was 1024 x 2B scalar write-through stores -- the round-5 bottleneck).
// Barrier: 1 tag per block in its own 128B sector; wave0-only poll with backoff.
__global__ __launch_bounds__(256, 1)
void gru_seq(const unsigned short* __restrict__ W3,   // [3072][1024] bf16
             const unsigned short* __restrict__ gi,   // [nsteps][64][3072] bf16
             unsigned short* __restrict__ seq,        // [256][64][1024] bf16
             float* __restrict__ hstate,              // [64][1024] f32 carry
             unsigned int* __restrict__ tags,         // 64 tags, 128B apart, zeroed
             int t0, int dir, int out_off, int nsteps)
{
  __shared__ __align__(16) uint4 Wf[32][3][64];        // 96KB
  __shared__ __align__(16) unsigned short hb2[64][16]; // 2KB transpose buffer
  const int tid  = threadIdx.x;
  const int bid  = blockIdx.x;
  const int c0   = bid * 16;
  const int wid  = tid >> 6, lane = tid & 63;
  const int fr   = lane & 15, q = lane >> 4;
  const int rowb = wid*16 + q*4;                      // first of this thread's 4 C rows
  const int arow = wid*16 + fr;                       // this lane's A-fragment row

  for (int ks = wid*8; ks < wid*8 + 8; ++ks)
    #pragma unroll
    for (int g = 0; g < 3; ++g)
      Wf[ks][g][lane] = *(const uint4*)(W3 + (size_t)(g*HD + c0 + fr)*HD + ks*32 + q*8);

  float hc[4];
  if (t0 == 0){
    hc[0] = hc[1] = hc[2] = hc[3] = 0.f;
  } else {
    #pragma unroll
    for (int r = 0; r < 4; ++r)
      hc[r] = hstate[(size_t)(rowb + r)*HD + c0 + fr];
  }
  __syncthreads();

  for (int tt = 0; tt < nsteps; ++tt){
    const int t = t0 + tt;

    // gate inputs for THIS step: issue early (plain loads, overlap the tag poll)
    unsigned short g_ir[4], g_iz[4], g_in[4];
    {
      const unsigned short* gb = gi + (size_t)tt*NB*H3;
      #pragma unroll
      for (int r = 0; r < 4; ++r){
        const unsigned short* p = gb + (size_t)(rowb + r)*H3 + c0 + fr;
        g_ir[r] = p[0];
        g_iz[r] = p[HD];
        g_in[r] = p[2*HD];
      }
    }

    f32x4 aR = (f32x4){0.f,0.f,0.f,0.f};
    f32x4 aZ = (f32x4){0.f,0.f,0.f,0.f};
    f32x4 aN = (f32x4){0.f,0.f,0.f,0.f};

    if (t > 0){
      if (tt >= 1) wait_tags(tags, (unsigned int)tt);
      const unsigned short* hp = seq + (size_t)(out_off + dir*(t-1))*NB*HD
                                     + (size_t)arow*HD + q*8;
      uint4 A[32];
      #pragma unroll
      for (int ks = 0; ks < 32; ++ks)
        A[ks] = *(const uint4*)(hp + ks*32);
      #pragma unroll
      for (int ks = 0; ks < 32; ++ks){
        bf16x8 a = *(const bf16x8*)&A[ks];
        aR = __builtin_amdgcn_mfma_f32_16x16x32_bf16(a, *(const bf16x8*)&Wf[ks][0][lane], aR, 0, 0, 0);
        aZ = __builtin_amdgcn_mfma_f32_16x16x32_bf16(a, *(const bf16x8*)&Wf[ks][1][lane], aZ, 0, 0, 0);
        aN = __builtin_amdgcn_mfma_f32_16x16x32_bf16(a, *(const bf16x8*)&Wf[ks][2][lane], aN, 0, 0, 0);
      }
    }

    // gate math (fp32, in-register) -> LDS transpose buffer
    #pragma unroll
    for (int r = 0; r < 4; ++r){
      float rr = fsigmoid(bf2f(g_ir[r]) + aR[r]);
      float zz = fsigmoid(bf2f(g_iz[r]) + aZ[r]);
      float nn = ftanh(bf2f(g_in[r]) + rr * aN[r]);
      hc[r] = (1.f - zz) * nn + zz * hc[r];
      hb2[rowb + r][fr] = f2bf(hc[r]);
    }
    __syncthreads();
    // wide coalesced write-through: 128 lanes x 16B
    if (tid < 128){
      int row = tid >> 1, hh = (tid & 1) * 8;
      u32x4 v = *(const u32x4*)&hb2[row][hh];
      st16_sc(seq + (size_t)(out_off + dir*t)*NB*HD + (size_t)row*HD + c0 + hh, v);
    }
    if (tt < nsteps - 1){
      vwait<0>();                 // own stores acked at coherence point
      __syncthreads();            // all lanes' stores acked
      if (tid == 0) st4_sc(tags + bid*32, (unsigned int)(tt + 1));
    }
  }

  #pragma unroll
  for (int r = 0; r < 4; ++r)
    hstate[(size_t)(rowb + r)*HD + c0 + fr] = hc[r];
}

// ---------------- z = eps*enc_std + enc_mean (bf16 out) ----------------
__global__ void z_make(const float* __restrict__ eps, const float* __restrict__ em,
                       const float* __restrict__ es, unsigned short* __restrict__ zb, int n){
  for (int i = blockIdx.x*blockDim.x + threadIdx.x; i < n; i += gridDim.x*blockDim.x)
    zb[i] = f2bf(eps[i] * es[i] + em[i]);
}

// ---------------- reductions ----------------
__global__ void kld_partial(const float* __restrict__ em, const float* __restrict__ es,
                            const float* __restrict__ pm, const float* __restrict__ ps,
                            float* __restrict__ part, int n){
  float s = 0.f;
  for (int i = blockIdx.x*blockDim.x + threadIdx.x; i < n; i += gridDim.x*blockDim.x){
    float e = es[i], p = ps[i], d = em[i] - pm[i];
    s += 2.f*(logf(p) - logf(e)) + (e*e + d*d)/(p*p) - 1.f;
  }
  __shared__ float red[256];
  red[threadIdx.x] = s; __syncthreads();
  for (int off = 128; off; off >>= 1){
    if (threadIdx.x < off) red[threadIdx.x] += red[threadIdx.x + off];
    __syncthreads();
  }
  if (threadIdx.x == 0) part[blockIdx.x] = red[0];
}

__global__ void nll_partial(const float* __restrict__ y, const float* __restrict__ dm,
                            float* __restrict__ part, int n){
  float s = 0.f;
  for (int i = blockIdx.x*blockDim.x + threadIdx.x; i < n; i += gridDim.x*blockDim.x){
    float yy = y[i], d = dm[i];
    s += yy * logf(d) + (1.f - yy) * logf(1.f - d);
  }
  __shared__ float red[256];
  red[threadIdx.x] = s; __syncthreads();
  for (int off = 128; off; off >>= 1){
    if (threadIdx.x < off) red[threadIdx.x] += red[threadIdx.x + off];
    __syncthreads();
  }
  if (threadIdx.x == 0) part[blockIdx.x] = red[0];
}

__global__ void final_sum(const float* __restrict__ part, int n, float scale, float* __restrict__ out){
  float s = 0.f;
  for (int i = threadIdx.x; i < n; i += 256) s += part[i];
  __shared__ float red[256];
  red[threadIdx.x] = s; __syncthreads();
  for (int off = 128; off; off >>= 1){
    if (threadIdx.x < off) red[threadIdx.x] += red[threadIdx.x + off];
    __syncthreads();
  }
  if (threadIdx.x == 0) out[0] = scale * red[0];
}

// ---------------- host ----------------
extern "C" void kernel_launch(void* const* d_in, const int* in_sizes, int n_in,
                              void* d_out, int out_size, void* d_ws, size_t ws_size,
                              hipStream_t stream)
{
  const float* x   = (const float*)d_in[0];
  const float* y   = (const float*)d_in[1];
  const float* eps = (const float*)d_in[2];
  const float* enc_b1 = (const float*)d_in[8];
  const float* enc_b2 = (const float*)d_in[10];
  const float* encm_b = (const float*)d_in[12];
  const float* encs_b = (const float*)d_in[14];
  const float* pr_b   = (const float*)d_in[16];
  const float* prm_b  = (const float*)d_in[18];
  const float* prs_b  = (const float*)d_in[20];
  const float* dec_b1 = (const float*)d_in[22];
  const float* dec_b2 = (const float*)d_in[24];
  const float* decm_b = (const float*)d_in[26];
  const float* decs_b = (const float*)d_in[28];

  // ---- workspace layout (total ~164 MiB) ----
  char* ws = (char*)d_ws;
  size_t off = 0;
  auto alloc = [&](size_t bytes){ size_t o = off; off += (bytes + 255) & ~(size_t)255; return o; };
  const size_t o_big   = alloc((size_t)71303168);       // 68 MiB phase-union region
  const size_t o_hseq  = alloc((size_t)TBM * HD * 2);   // h_seq bf16 (32 MiB)
  const size_t o_aseq  = alloc((size_t)TBM * HD * 2);   // a_fwd bf16 (32 MiB)
  const size_t o_wbf   = alloc((size_t)16384000 * 2);   // all weights bf16 (~31.3 MiB)
  const size_t o_hst   = alloc((size_t)NB * HD * 4);    // f32 h carry between chunk launches
  const size_t o_bar   = alloc((size_t)32768);          // 4 x 64 tags (128B apart)
  const size_t o_pkld  = alloc((size_t)1024 * 4);
  const size_t o_pnll  = alloc((size_t)1024 * 4);
  (void)off; (void)ws_size;

  char* big = ws + o_big;
  unsigned short* gih = (unsigned short*)(big);
  unsigned short* xbf = (unsigned short*)(big + 50331648);
  unsigned short* ybf = (unsigned short*)(big + 54525952);
  unsigned short* tA  = (unsigned short*)(big);
  unsigned short* tB  = (unsigned short*)(big + 33554432);
  unsigned short* zbf = (unsigned short*)(big + 67108864);

  unsigned short* hseq = (unsigned short*)(ws + o_hseq);
  unsigned short* aseq = (unsigned short*)(ws + o_aseq);
  unsigned short* wbf  = (unsigned short*)(ws + o_wbf);
  float* hstate = (float*)(ws + o_hst);
  unsigned int* bar = (unsigned int*)(ws + o_bar);
  float* pkld = (float*)(ws + o_pkld);
  float* pnll = (float*)(ws + o_pnll);

  const int   widx[15] = {3,4,5,6,7,9,11,13,15,17,19,21,23,25,27};
  const size_t wsz[15] = {393216,3145728,3538944,3145728,1048576,1048576,131072,131072,
                          1048576,131072,131072,1179648,1048576,131072,131072};
  size_t woff[15]; { size_t a = 0; for (int i = 0; i < 15; ++i){ woff[i] = a; a += wsz[i]; } }
  unsigned short* w_hWih = wbf + woff[0];
  unsigned short* w_hWhh = wbf + woff[1];
  unsigned short* w_aWih = wbf + woff[2];
  unsigned short* w_aWhh = wbf + woff[3];
  unsigned short* w_enc1 = wbf + woff[4];
  unsigned short* w_enc2 = wbf + woff[5];
  unsigned short* w_encm = wbf + woff[6];
  unsigned short* w_encs = wbf + woff[7];
  unsigned short* w_pr   = wbf + woff[8];
  unsigned short* w_prm  = wbf + woff[9];
  unsigned short* w_prs  = wbf + woff[10];
  unsigned short* w_dec1 = wbf + woff[11];
  unsigned short* w_dec2 = wbf + woff[12];
  unsigned short* w_decm = wbf + woff[13];
  unsigned short* w_decs = wbf + woff[14];

  float* out = (float*)d_out;
  float* em_out = out + 2;
  float* es_out = out + 2 + 2097152;
  float* dm_out = out + 2 + 2*2097152;   // doubles as pm scratch before decoder
  float* ds_out = out + 2 + 3*2097152;   // doubles as ps scratch before decoder
  float* pm = dm_out;
  float* ps = ds_out;

  // --- converts + tag init ---
  cvt_bf16<<<256, 256, 0, stream>>>(x, xbf, TBM*XD);
  cvt_bf16<<<256, 256, 0, stream>>>(y, ybf, TBM*XD);
  for (int i = 0; i < 15; ++i)
    cvt_bf16<<<256, 256, 0, stream>>>((const float*)d_in[widx[i]], wbf + woff[i], (int)wsz[i]);
  (void)hipMemsetAsync(bar, 0, 32768, stream);

  const dim3 blk(256);
  const dim3 gHalf3072(H3/128, 64);     // 8192 rows
  const dim3 g1024(HD/128, TBM/128);
  const dim3 g128(1, TBM/128);

  // --- GRU 1 (time-chunked gi: 2 x 128 steps; persistent column-parallel kernel) ---
  for (int c = 0; c < 2; ++c){
    gemm_bf16<0,1,0><<<gHalf3072, blk, 0, stream>>>(xbf, 0, XD, (const unsigned short*)nullptr, 0, XD,
                                                    w_hWih, nullptr, gih, H3, c*8192);
    gru_seq<<<64, 256, 0, stream>>>(w_hWhh, gih, hseq, hstate, bar + c*2048,
                                    c*128, +1, 0, 128);
  }

  // --- GRU 2 (input [y_rev | h_rev], output written reversed => a_fwd) ---
  for (int c = 0; c < 2; ++c){
    gemm_bf16<0,1,0><<<gHalf3072, blk, 0, stream>>>(ybf, 1, XD, hseq, 1, XD + HD,
                                                    w_aWih, nullptr, gih, H3, c*8192);
    gru_seq<<<64, 256, 0, stream>>>(w_aWhh, gih, aseq, hstate, bar + (2 + c)*2048,
                                    c*128, -1, 255, 128);
  }

  // --- encoder ---
  gemm_bf16<1,1,1><<<g1024, blk, 0, stream>>>(aseq, 0, HD, (const unsigned short*)nullptr, 0, HD,
                                              w_enc1, enc_b1, tA, HD, 0);
  gemm_bf16<1,1,1><<<g1024, blk, 0, stream>>>(tA, 0, HD, (const unsigned short*)nullptr, 0, HD,
                                              w_enc2, enc_b2, tB, HD, 0);
  gemm_bf16<0,0,1><<<g128, blk, 0, stream>>>(tB, 0, HD, (const unsigned short*)nullptr, 0, HD,
                                             w_encm, encm_b, em_out, ZD, 0);
  gemm_bf16<3,0,1><<<g128, blk, 0, stream>>>(tB, 0, HD, (const unsigned short*)nullptr, 0, HD,
                                             w_encs, encs_b, es_out, ZD, 0);
  z_make<<<2048, 256, 0, stream>>>(eps, em_out, es_out, zbf, TBM*ZD);

  // --- prior (pm/ps into dm/ds regions; kld BEFORE decoder overwrites them) ---
  gemm_bf16<1,1,1><<<g1024, blk, 0, stream>>>(hseq, 1, HD, (const unsigned short*)nullptr, 1, HD,
                                              w_pr, pr_b, tA, HD, 0);
  gemm_bf16<0,0,1><<<g128, blk, 0, stream>>>(tA, 0, HD, (const unsigned short*)nullptr, 0, HD,
                                             w_prm, prm_b, pm, ZD, 0);
  gemm_bf16<3,0,1><<<g128, blk, 0, stream>>>(tA, 0, HD, (const unsigned short*)nullptr, 0, HD,
                                             w_prs, prs_b, ps, ZD, 0);
  kld_partial<<<1024, 256, 0, stream>>>(em_out, es_out, pm, ps, pkld, TBM*ZD);
  final_sum<<<1, 256, 0, stream>>>(pkld, 1024, 0.5f, out + 0);

  // --- decoder ---
  gemm_bf16<1,1,1><<<g1024, blk, 0, stream>>>(zbf, 0, ZD, hseq, 1, ZD + HD,
                                              w_dec1, dec_b1, tA, HD, 0);
  gemm_bf16<1,1,1><<<g1024, blk, 0, stream>>>(tA, 0, HD, (const unsigned short*)nullptr, 0, HD,
                                              w_dec2, dec_b2, tB, HD, 0);
  gemm_bf16<2,0,1><<<g128, blk, 0, stream>>>(tB, 0, HD, (const unsigned short*)nullptr, 0, HD,
                                             w_decm, decm_b, dm_out, ZD, 0);
  gemm_bf16<3,0,1><<<g128, blk, 0, stream>>>(tB, 0, HD, (const unsigned short*)nullptr, 0, HD,
                                             w_decs, decs_b, ds_out, ZD, 0);

  // --- nll ---
  nll_partial<<<1024, 256, 0, stream>>>(y, dm_out, pnll, TBM*XD);
  final_sum<<<1, 256, 0, stream>>>(pnll, 1024, -1.0f, out + 1);
}

// Round 8
// 4819.117 us; speedup vs baseline: 4.0410x; 1.1004x over previous
//
#include <hip/hip_runtime.h>
#include <cstdint>
#include <cstddef>

// Problem dims
#define NT   256     // T
#define NB   64      // B
#define XD   128
#define HD   1024
#define ZD   128
#define H3   3072
#define TBM  16384   // T*B

typedef __attribute__((ext_vector_type(8))) short bf16x8;
typedef __attribute__((ext_vector_type(4))) float f32x4;
typedef __attribute__((ext_vector_type(4))) unsigned int u32x4;

__device__ __forceinline__ unsigned short f2bf(float f){
  unsigned int u = __float_as_uint(f);
  u += 0x7fffu + ((u >> 16) & 1u);
  return (unsigned short)(u >> 16);
}
__device__ __forceinline__ float bf2f(unsigned short h){
  return __uint_as_float(((unsigned int)h) << 16);
}

// ---- coherent (L2-bypass) store helpers: sc0 sc1 write through to the L3 coherence point ----
__device__ __forceinline__ void st16_sc(unsigned short* p, u32x4 v){
  asm volatile("global_store_dwordx4 %0, %1, off sc0 sc1" :: "v"(p), "v"(v) : "memory");
}
__device__ __forceinline__ void st4_sc(unsigned int* p, unsigned int v){
  asm volatile("global_store_dword %0, %1, off sc0 sc1" :: "v"(p), "v"(v) : "memory");
}
template<int N>
__device__ __forceinline__ void vwait(){
  asm volatile("s_waitcnt vmcnt(%0)" :: "i"(N) : "memory");
  __builtin_amdgcn_sched_barrier(0);
}

// fast gates
__device__ __forceinline__ float fsigmoid(float x){
  return 1.f / (1.f + __expf(-x));
}
__device__ __forceinline__ float ftanh(float x){
  float xc = fminf(fmaxf(x, -15.f), 15.f);
  float e = __expf(2.f * xc);
  return (e - 1.f) / (e + 1.f);
}

// wave0 polls 64 spread tags (128B apart, sc0sc1 = L2-bypass); other waves park at barrier.
__device__ __forceinline__ void wait_tags(const unsigned int* tags, unsigned int target){
  if (threadIdx.x < 64){
    const unsigned int* p = tags + threadIdx.x * 32;   // 128B spacing
    for (;;){
      unsigned int v;
      asm volatile("global_load_dword %0, %1, off sc0 sc1\n\ts_waitcnt vmcnt(0)"
                   : "=v"(v) : "v"(p) : "memory");
      if (__all((int)(v >= target))) break;
      __builtin_amdgcn_s_sleep(2);
    }
  }
  __syncthreads();
}

// ---------------- convert f32 -> bf16 ----------------
__global__ void cvt_bf16(const float* __restrict__ src, unsigned short* __restrict__ dst, int n){
  for (int i = blockIdx.x*blockDim.x + threadIdx.x; i < n; i += gridDim.x*blockDim.x)
    dst[i] = f2bf(src[i]);
}

// ---------------- generic bf16 MFMA GEMM (unchanged) ----------------
template<int ACT, int OUT_BF, int BIAS>
__launch_bounds__(256)
__global__ void gemm_bf16(const unsigned short* __restrict__ A1, int rev1, int K1,
                          const unsigned short* __restrict__ A2, int rev2, int K,
                          const unsigned short* __restrict__ W,
                          const float* __restrict__ bias,
                          void* __restrict__ Cv, int N, int m0)
{
  __shared__ __align__(16) unsigned short As[128][40];
  __shared__ __align__(16) unsigned short Ws[128][40];
  const int tid   = threadIdx.x;
  const int mbase = blockIdx.y * 128;
  const int nbase = blockIdx.x * 128;
  const int wid = tid >> 6, lane = tid & 63;
  const int wr = wid >> 1, wc = wid & 1;
  const int fr = lane & 15;
  const int kc = (lane >> 4) * 8;
  const int K2 = K - K1;
  const int nk = K >> 5;

  f32x4 acc[4][4];
  #pragma unroll
  for (int i = 0; i < 4; ++i)
    #pragma unroll
    for (int j = 0; j < 4; ++j)
      acc[i][j] = (f32x4){0.f, 0.f, 0.f, 0.f};

  for (int ks = 0; ks < nk; ++ks){
    const int k0 = ks << 5;
    __syncthreads();
    for (int l = tid; l < 512; l += 256){
      int row = l >> 2, c = l & 3;
      int kk = k0 + c*8;
      int m = m0 + mbase + row;
      uint4 v;
      if (kk < K1){
        int mm = rev1 ? (((255 - (m >> 6)) << 6) | (m & 63)) : m;
        v = *(const uint4*)(A1 + (size_t)mm * K1 + kk);
      } else {
        int mm = rev2 ? (((255 - (m >> 6)) << 6) | (m & 63)) : m;
        v = *(const uint4*)(A2 + (size_t)mm * K2 + (kk - K1));
      }
      *(uint4*)&As[row][c*8] = v;
    }
    for (int l = tid; l < 512; l += 256){
      int row = l >> 2, c = l & 3;
      uint4 v = *(const uint4*)(W + (size_t)(nbase + row) * K + k0 + c*8);
      *(uint4*)&Ws[row][c*8] = v;
    }
    __syncthreads();
    bf16x8 af[4], bfm[4];
    #pragma unroll
    for (int f = 0; f < 4; ++f) af[f]  = *(const bf16x8*)&As[wr*64 + f*16 + fr][kc];
    #pragma unroll
    for (int f = 0; f < 4; ++f) bfm[f] = *(const bf16x8*)&Ws[wc*64 + f*16 + fr][kc];
    #pragma unroll
    for (int i = 0; i < 4; ++i)
      #pragma unroll
      for (int j = 0; j < 4; ++j)
        acc[i][j] = __builtin_amdgcn_mfma_f32_16x16x32_bf16(af[i], bfm[j], acc[i][j], 0, 0, 0);
  }

  #pragma unroll
  for (int i = 0; i < 4; ++i){
    #pragma unroll
    for (int j = 0; j < 4; ++j){
      #pragma unroll
      for (int r = 0; r < 4; ++r){
        int row = mbase + wr*64 + i*16 + (lane >> 4)*4 + r;
        int col = nbase + wc*64 + j*16 + fr;
        float v = acc[i][j][r];
        if (BIAS) v += bias[col];
        if (ACT == 1) v = fmaxf(v, 0.f);
        else if (ACT == 2) v = 1.f / (1.f + expf(-v));
        else if (ACT == 3) v = (v > 20.f) ? v : log1pf(expf(v));
        if (OUT_BF) ((unsigned short*)Cv)[(size_t)row * N + col] = f2bf(v);
        else        ((float*)Cv)[(size_t)row * N + col] = v;
      }
    }
  }
}

// ---------------- persistent GRU sequence kernel (v5) ----------------
// 64 blocks x 256 threads. Block b owns output columns [16b,16b+16) of all 3 gates.
// W slice (3x16x1024 bf16 = 96KB) in LDS (MFMA B-fragment order), loaded once.
// h(t-1): ALL 32 16B fragments issued as asm-pinned loads (128 VGPRs forced live),
//   consumed in 4 batches with counted vmcnt(24/16/8/0) -> ONE exposed L3 latency.
// h(t) write: 2KB LDS transpose -> 128 x 16B sc0sc1 write-through stores.
// Barrier: 1 tag per block in its own 128B sector; wave0-only poll with backoff.
__global__ __launch_bounds__(256, 1)
void gru_seq(const unsigned short* __restrict__ W3,   // [3072][1024] bf16
             const unsigned short* __restrict__ gi,   // [nsteps][64][3072] bf16
             unsigned short* __restrict__ seq,        // [256][64][1024] bf16
             float* __restrict__ hstate,              // [64][1024] f32 carry
             unsigned int* __restrict__ tags,         // 64 tags, 128B apart, zeroed
             int t0, int dir, int out_off, int nsteps)
{
  __shared__ __align__(16) uint4 Wf[32][3][64];        // 96KB
  __shared__ __align__(16) unsigned short hb2[64][16]; // 2KB transpose buffer
  const int tid  = threadIdx.x;
  const int bid  = blockIdx.x;
  const int c0   = bid * 16;
  const int wid  = tid >> 6, lane = tid & 63;
  const int fr   = lane & 15, q = lane >> 4;
  const int rowb = wid*16 + q*4;                      // first of this thread's 4 C rows
  const int arow = wid*16 + fr;                       // this lane's A-fragment row

  for (int ks = wid*8; ks < wid*8 + 8; ++ks)
    #pragma unroll
    for (int g = 0; g < 3; ++g)
      Wf[ks][g][lane] = *(const uint4*)(W3 + (size_t)(g*HD + c0 + fr)*HD + ks*32 + q*8);

  float hc[4];
  if (t0 == 0){
    hc[0] = hc[1] = hc[2] = hc[3] = 0.f;
  } else {
    #pragma unroll
    for (int r = 0; r < 4; ++r)
      hc[r] = hstate[(size_t)(rowb + r)*HD + c0 + fr];
  }
  __syncthreads();

  for (int tt = 0; tt < nsteps; ++tt){
    const int t = t0 + tt;

    // gate inputs for THIS step: issue early (plain loads, overlap the tag poll)
    unsigned short g_ir[4], g_iz[4], g_in[4];
    {
      const unsigned short* gb = gi + (size_t)tt*NB*H3;
      #pragma unroll
      for (int r = 0; r < 4; ++r){
        const unsigned short* p = gb + (size_t)(rowb + r)*H3 + c0 + fr;
        g_ir[r] = p[0];
        g_iz[r] = p[HD];
        g_in[r] = p[2*HD];
      }
    }

    f32x4 aR = (f32x4){0.f,0.f,0.f,0.f};
    f32x4 aZ = (f32x4){0.f,0.f,0.f,0.f};
    f32x4 aN = (f32x4){0.f,0.f,0.f,0.f};

    if (t > 0){
      if (tt >= 1) wait_tags(tags, (unsigned int)tt);
      const unsigned short* hp = seq + (size_t)(out_off + dir*(t-1))*NB*HD
                                     + (size_t)arow*HD + q*8;
      // issue ALL 32 fragment loads; asm outputs force 128 VGPRs live -> one latency
      u32x4 A[32];
      #pragma unroll
      for (int ks = 0; ks < 32; ++ks)
        asm volatile("global_load_dwordx4 %0, %1, off offset:%2"
                     : "=v"(A[ks]) : "v"(hp), "i"(ks*64));
      #pragma unroll
      for (int b4 = 0; b4 < 4; ++b4){
        if (b4 == 0) vwait<24>();
        else if (b4 == 1) vwait<16>();
        else if (b4 == 2) vwait<8>();
        else vwait<0>();
        #pragma unroll
        for (int k8 = 0; k8 < 8; ++k8){
          const int ks = b4*8 + k8;
          bf16x8 a = *(const bf16x8*)&A[ks];
          aR = __builtin_amdgcn_mfma_f32_16x16x32_bf16(a, *(const bf16x8*)&Wf[ks][0][lane], aR, 0, 0, 0);
          aZ = __builtin_amdgcn_mfma_f32_16x16x32_bf16(a, *(const bf16x8*)&Wf[ks][1][lane], aZ, 0, 0, 0);
          aN = __builtin_amdgcn_mfma_f32_16x16x32_bf16(a, *(const bf16x8*)&Wf[ks][2][lane], aN, 0, 0, 0);
        }
      }
    }

    // gate math (fp32, in-register) -> LDS transpose buffer
    #pragma unroll
    for (int r = 0; r < 4; ++r){
      float rr = fsigmoid(bf2f(g_ir[r]) + aR[r]);
      float zz = fsigmoid(bf2f(g_iz[r]) + aZ[r]);
      float nn = ftanh(bf2f(g_in[r]) + rr * aN[r]);
      hc[r] = (1.f - zz) * nn + zz * hc[r];
      hb2[rowb + r][fr] = f2bf(hc[r]);
    }
    __syncthreads();
    // wide coalesced write-through: 128 lanes x 16B
    if (tid < 128){
      int row = tid >> 1, hh = (tid & 1) * 8;
      u32x4 v = *(const u32x4*)&hb2[row][hh];
      st16_sc(seq + (size_t)(out_off + dir*t)*NB*HD + (size_t)row*HD + c0 + hh, v);
    }
    if (tt < nsteps - 1){
      vwait<0>();                 // own stores acked at coherence point
      __syncthreads();            // all lanes' stores acked
      if (tid == 0) st4_sc(tags + bid*32, (unsigned int)(tt + 1));
    }
  }

  #pragma unroll
  for (int r = 0; r < 4; ++r)
    hstate[(size_t)(rowb + r)*HD + c0 + fr] = hc[r];
}

// ---------------- z = eps*enc_std + enc_mean (bf16 out) ----------------
__global__ void z_make(const float* __restrict__ eps, const float* __restrict__ em,
                       const float* __restrict__ es, unsigned short* __restrict__ zb, int n){
  for (int i = blockIdx.x*blockDim.x + threadIdx.x; i < n; i += gridDim.x*blockDim.x)
    zb[i] = f2bf(eps[i] * es[i] + em[i]);
}

// ---------------- reductions ----------------
__global__ void kld_partial(const float* __restrict__ em, const float* __restrict__ es,
                            const float* __restrict__ pm, const float* __restrict__ ps,
                            float* __restrict__ part, int n){
  float s = 0.f;
  for (int i = blockIdx.x*blockDim.x + threadIdx.x; i < n; i += gridDim.x*blockDim.x){
    float e = es[i], p = ps[i], d = em[i] - pm[i];
    s += 2.f*(logf(p) - logf(e)) + (e*e + d*d)/(p*p) - 1.f;
  }
  __shared__ float red[256];
  red[threadIdx.x] = s; __syncthreads();
  for (int off = 128; off; off >>= 1){
    if (threadIdx.x < off) red[threadIdx.x] += red[threadIdx.x + off];
    __syncthreads();
  }
  if (threadIdx.x == 0) part[blockIdx.x] = red[0];
}

__global__ void nll_partial(const float* __restrict__ y, const float* __restrict__ dm,
                            float* __restrict__ part, int n){
  float s = 0.f;
  for (int i = blockIdx.x*blockDim.x + threadIdx.x; i < n; i += gridDim.x*blockDim.x){
    float yy = y[i], d = dm[i];
    s += yy * logf(d) + (1.f - yy) * logf(1.f - d);
  }
  __shared__ float red[256];
  red[threadIdx.x] = s; __syncthreads();
  for (int off = 128; off; off >>= 1){
    if (threadIdx.x < off) red[threadIdx.x] += red[threadIdx.x + off];
    __syncthreads();
  }
  if (threadIdx.x == 0) part[blockIdx.x] = red[0];
}

__global__ void final_sum(const float* __restrict__ part, int n, float scale, float* __restrict__ out){
  float s = 0.f;
  for (int i = threadIdx.x; i < n; i += 256) s += part[i];
  __shared__ float red[256];
  red[threadIdx.x] = s; __syncthreads();
  for (int off = 128; off; off >>= 1){
    if (threadIdx.x < off) red[threadIdx.x] += red[threadIdx.x + off];
    __syncthreads();
  }
  if (threadIdx.x == 0) out[0] = scale * red[0];
}

// ---------------- host ----------------
extern "C" void kernel_launch(void* const* d_in, const int* in_sizes, int n_in,
                              void* d_out, int out_size, void* d_ws, size_t ws_size,
                              hipStream_t stream)
{
  const float* x   = (const float*)d_in[0];
  const float* y   = (const float*)d_in[1];
  const float* eps = (const float*)d_in[2];
  const float* enc_b1 = (const float*)d_in[8];
  const float* enc_b2 = (const float*)d_in[10];
  const float* encm_b = (const float*)d_in[12];
  const float* encs_b = (const float*)d_in[14];
  const float* pr_b   = (const float*)d_in[16];
  const float* prm_b  = (const float*)d_in[18];
  const float* prs_b  = (const float*)d_in[20];
  const float* dec_b1 = (const float*)d_in[22];
  const float* dec_b2 = (const float*)d_in[24];
  const float* decm_b = (const float*)d_in[26];
  const float* decs_b = (const float*)d_in[28];

  // ---- workspace layout (total ~164 MiB) ----
  char* ws = (char*)d_ws;
  size_t off = 0;
  auto alloc = [&](size_t bytes){ size_t o = off; off += (bytes + 255) & ~(size_t)255; return o; };
  const size_t o_big   = alloc((size_t)71303168);       // 68 MiB phase-union region
  const size_t o_hseq  = alloc((size_t)TBM * HD * 2);   // h_seq bf16 (32 MiB)
  const size_t o_aseq  = alloc((size_t)TBM * HD * 2);   // a_fwd bf16 (32 MiB)
  const size_t o_wbf   = alloc((size_t)16384000 * 2);   // all weights bf16 (~31.3 MiB)
  const size_t o_hst   = alloc((size_t)NB * HD * 4);    // f32 h carry between chunk launches
  const size_t o_bar   = alloc((size_t)32768);          // 4 x 64 tags (128B apart)
  const size_t o_pkld  = alloc((size_t)1024 * 4);
  const size_t o_pnll  = alloc((size_t)1024 * 4);
  (void)off; (void)ws_size;

  char* big = ws + o_big;
  unsigned short* gih = (unsigned short*)(big);
  unsigned short* xbf = (unsigned short*)(big + 50331648);
  unsigned short* ybf = (unsigned short*)(big + 54525952);
  unsigned short* tA  = (unsigned short*)(big);
  unsigned short* tB  = (unsigned short*)(big + 33554432);
  unsigned short* zbf = (unsigned short*)(big + 67108864);

  unsigned short* hseq = (unsigned short*)(ws + o_hseq);
  unsigned short* aseq = (unsigned short*)(ws + o_aseq);
  unsigned short* wbf  = (unsigned short*)(ws + o_wbf);
  float* hstate = (float*)(ws + o_hst);
  unsigned int* bar = (unsigned int*)(ws + o_bar);
  float* pkld = (float*)(ws + o_pkld);
  float* pnll = (float*)(ws + o_pnll);

  const int   widx[15] = {3,4,5,6,7,9,11,13,15,17,19,21,23,25,27};
  const size_t wsz[15] = {393216,3145728,3538944,3145728,1048576,1048576,131072,131072,
                          1048576,131072,131072,1179648,1048576,131072,131072};
  size_t woff[15]; { size_t a = 0; for (int i = 0; i < 15; ++i){ woff[i] = a; a += wsz[i]; } }
  unsigned short* w_hWih = wbf + woff[0];
  unsigned short* w_hWhh = wbf + woff[1];
  unsigned short* w_aWih = wbf + woff[2];
  unsigned short* w_aWhh = wbf + woff[3];
  unsigned short* w_enc1 = wbf + woff[4];
  unsigned short* w_enc2 = wbf + woff[5];
  unsigned short* w_encm = wbf + woff[6];
  unsigned short* w_encs = wbf + woff[7];
  unsigned short* w_pr   = wbf + woff[8];
  unsigned short* w_prm  = wbf + woff[9];
  unsigned short* w_prs  = wbf + woff[10];
  unsigned short* w_dec1 = wbf + woff[11];
  unsigned short* w_dec2 = wbf + woff[12];
  unsigned short* w_decm = wbf + woff[13];
  unsigned short* w_decs = wbf + woff[14];

  float* out = (float*)d_out;
  float* em_out = out + 2;
  float* es_out = out + 2 + 2097152;
  float* dm_out = out + 2 + 2*2097152;   // doubles as pm scratch before decoder
  float* ds_out = out + 2 + 3*2097152;   // doubles as ps scratch before decoder
  float* pm = dm_out;
  float* ps = ds_out;

  // --- converts + tag init ---
  cvt_bf16<<<256, 256, 0, stream>>>(x, xbf, TBM*XD);
  cvt_bf16<<<256, 256, 0, stream>>>(y, ybf, TBM*XD);
  for (int i = 0; i < 15; ++i)
    cvt_bf16<<<256, 256, 0, stream>>>((const float*)d_in[widx[i]], wbf + woff[i], (int)wsz[i]);
  (void)hipMemsetAsync(bar, 0, 32768, stream);

  const dim3 blk(256);
  const dim3 gHalf3072(H3/128, 64);     // 8192 rows
  const dim3 g1024(HD/128, TBM/128);
  const dim3 g128(1, TBM/128);

  // --- GRU 1 (time-chunked gi: 2 x 128 steps; persistent column-parallel kernel) ---
  for (int c = 0; c < 2; ++c){
    gemm_bf16<0,1,0><<<gHalf3072, blk, 0, stream>>>(xbf, 0, XD, (const unsigned short*)nullptr, 0, XD,
                                                    w_hWih, nullptr, gih, H3, c*8192);
    gru_seq<<<64, 256, 0, stream>>>(w_hWhh, gih, hseq, hstate, bar + c*2048,
                                    c*128, +1, 0, 128);
  }

  // --- GRU 2 (input [y_rev | h_rev], output written reversed => a_fwd) ---
  for (int c = 0; c < 2; ++c){
    gemm_bf16<0,1,0><<<gHalf3072, blk, 0, stream>>>(ybf, 1, XD, hseq, 1, XD + HD,
                                                    w_aWih, nullptr, gih, H3, c*8192);
    gru_seq<<<64, 256, 0, stream>>>(w_aWhh, gih, aseq, hstate, bar + (2 + c)*2048,
                                    c*128, -1, 255, 128);
  }

  // --- encoder ---
  gemm_bf16<1,1,1><<<g1024, blk, 0, stream>>>(aseq, 0, HD, (const unsigned short*)nullptr, 0, HD,
                                              w_enc1, enc_b1, tA, HD, 0);
  gemm_bf16<1,1,1><<<g1024, blk, 0, stream>>>(tA, 0, HD, (const unsigned short*)nullptr, 0, HD,
                                              w_enc2, enc_b2, tB, HD, 0);
  gemm_bf16<0,0,1><<<g128, blk, 0, stream>>>(tB, 0, HD, (const unsigned short*)nullptr, 0, HD,
                                             w_encm, encm_b, em_out, ZD, 0);
  gemm_bf16<3,0,1><<<g128, blk, 0, stream>>>(tB, 0, HD, (const unsigned short*)nullptr, 0, HD,
                                             w_encs, encs_b, es_out, ZD, 0);
  z_make<<<2048, 256, 0, stream>>>(eps, em_out, es_out, zbf, TBM*ZD);

  // --- prior (pm/ps into dm/ds regions; kld BEFORE decoder overwrites them) ---
  gemm_bf16<1,1,1><<<g1024, blk, 0, stream>>>(hseq, 1, HD, (const unsigned short*)nullptr, 1, HD,
                                              w_pr, pr_b, tA, HD, 0);
  gemm_bf16<0,0,1><<<g128, blk, 0, stream>>>(tA, 0, HD, (const unsigned short*)nullptr, 0, HD,
                                             w_prm, prm_b, pm, ZD, 0);
  gemm_bf16<3,0,1><<<g128, blk, 0, stream>>>(tA, 0, HD, (const unsigned short*)nullptr, 0, HD,
                                             w_prs, prs_b, ps, ZD, 0);
  kld_partial<<<1024, 256, 0, stream>>>(em_out, es_out, pm, ps, pkld, TBM*ZD);
  final_sum<<<1, 256, 0, stream>>>(pkld, 1024, 0.5f, out + 0);

  // --- decoder ---
  gemm_bf16<1,1,1><<<g1024, blk, 0, stream>>>(zbf, 0, ZD, hseq, 1, ZD + HD,
                                              w_dec1, dec_b1, tA, HD, 0);
  gemm_bf16<1,1,1><<<g1024, blk, 0, stream>>>(tA, 0, HD, (const unsigned short*)nullptr, 0, HD,
                                              w_dec2, dec_b2, tB, HD, 0);
  gemm_bf16<2,0,1><<<g128, blk, 0, stream>>>(tB, 0, HD, (const unsigned short*)nullptr, 0, HD,
                                             w_decm, decm_b, dm_out, ZD, 0);
  gemm_bf16<3,0,1><<<g128, blk, 0, stream>>>(tB, 0, HD, (const unsigned short*)nullptr, 0, HD,
                                             w_decs, decs_b, ds_out, ZD, 0);

  // --- nll ---
  nll_partial<<<1024, 256, 0, stream>>>(y, dm_out, pnll, TBM*XD);
  final_sum<<<1, 256, 0, stream>>>(pnll, 1024, -1.0f, out + 1);
}